// Round 3
// baseline (299.932 us; speedup 1.0000x reference)
//
#include <hip/hip_runtime.h>
#include <hip/hip_bf16.h>

typedef __attribute__((ext_vector_type(4)))  float  f32x4;
typedef __attribute__((ext_vector_type(16))) float  f32x16;
typedef __attribute__((ext_vector_type(8)))  short  bf16x8;
typedef __attribute__((ext_vector_type(4)))  int    int32x4;
typedef __attribute__((ext_vector_type(2)))  unsigned int uint32x2;

#define DEVINL static __device__ __forceinline__

DEVINL ushort f2bf(float f) {
  unsigned u = __builtin_bit_cast(unsigned, f);
  unsigned r = u + 0x7fffu + ((u >> 16) & 1u);
  return (ushort)(r >> 16);
}

DEVINL unsigned cvtpk(float lo, float hi) {
  unsigned r;
  asm("v_cvt_pk_bf16_f32 %0, %1, %2" : "=v"(r) : "v"(lo), "v"(hi));
  return r;
}

DEVINL void plswap(unsigned &a, unsigned &b) {
  asm("v_permlane32_swap_b32 %0, %1" : "+v"(a), "+v"(b));
}

DEVINL float bf2f(short s) {
  return __builtin_bit_cast(float, ((unsigned)(ushort)s) << 16);
}

DEVINL f32x4 mfma16(bf16x8 a, bf16x8 b, f32x4 c) {
  return __builtin_amdgcn_mfma_f32_16x16x32_bf16(a, b, c, 0, 0, 0);
}
DEVINL f32x16 mfma32(bf16x8 a, bf16x8 b, f32x16 c) {
  return __builtin_amdgcn_mfma_f32_32x32x16_bf16(a, b, c, 0, 0, 0);
}

// ---------------------------------------------------------------- GEMM
// C = A @ B.  A [M,K] (f32 or bf16), B [K,N] f32 (cast to bf16 in staging).
// MODE 0: C f32 [M,N] + bias
// MODE 1: C bf16 scattered to [b,h,n,d]
// MODE 2: C bf16 scattered to [b,h,d,n]  (V transposed)
template<bool ABF, int MODE>
__global__ __launch_bounds__(256)
void gemm_k(const void* __restrict__ Ap, const float* __restrict__ Bp,
            void* __restrict__ Cp, const float* __restrict__ bias,
            int M, int N, int K)
{
  __shared__ ushort As[128 * 40];
  __shared__ ushort Bs[128 * 40];
  const int t  = threadIdx.x;
  const int m0 = blockIdx.y * 128, n0 = blockIdx.x * 128;
  const int lane = t & 63, w = t >> 6;
  const int wr = w >> 1, wc = w & 1;
  const int g = lane >> 4, ql = lane & 15;

  const int arow = t >> 1, akc = (t & 1) * 16;
  const int bgr = t >> 5, blc = (t & 31) * 4;

  f32x4 acc[4][4];
  #pragma unroll
  for (int i = 0; i < 4; i++)
    #pragma unroll
    for (int j = 0; j < 4; j++) acc[i][j] = (f32x4){0.f, 0.f, 0.f, 0.f};

  for (int k0 = 0; k0 < K; k0 += 32) {
    {
      ushort* dst = &As[arow * 40 + akc];
      if (ABF) {
        const ushort* ap = (const ushort*)Ap + (size_t)(m0 + arow) * K + k0 + akc;
        *(bf16x8*)dst       = *(const bf16x8*)ap;
        *(bf16x8*)(dst + 8) = *(const bf16x8*)(ap + 8);
      } else {
        const float* ap = (const float*)Ap + (size_t)(m0 + arow) * K + k0 + akc;
        f32x4 v0 = *(const f32x4*)(ap + 0);
        f32x4 v1 = *(const f32x4*)(ap + 4);
        f32x4 v2 = *(const f32x4*)(ap + 8);
        f32x4 v3 = *(const f32x4*)(ap + 12);
        bf16x8 h0, h1;
        #pragma unroll
        for (int i = 0; i < 4; i++) {
          h0[i]     = (short)f2bf(v0[i]);
          h0[i + 4] = (short)f2bf(v1[i]);
          h1[i]     = (short)f2bf(v2[i]);
          h1[i + 4] = (short)f2bf(v3[i]);
        }
        *(bf16x8*)dst       = h0;
        *(bf16x8*)(dst + 8) = h1;
      }
    }
    {
      const float* bp = Bp + (size_t)(k0 + bgr * 4) * N + n0 + blc;
      f32x4 r0 = *(const f32x4*)(bp);
      f32x4 r1 = *(const f32x4*)(bp + N);
      f32x4 r2 = *(const f32x4*)(bp + 2 * N);
      f32x4 r3 = *(const f32x4*)(bp + 3 * N);
      #pragma unroll
      for (int j = 0; j < 4; j++) {
        uint32x2 pr;
        pr[0] = ((unsigned)f2bf(r1[j]) << 16) | f2bf(r0[j]);
        pr[1] = ((unsigned)f2bf(r3[j]) << 16) | f2bf(r2[j]);
        *(uint32x2*)&Bs[(blc + j) * 40 + bgr * 4] = pr;
      }
    }
    __syncthreads();

    bf16x8 af[4], bfr[4];
    #pragma unroll
    for (int i = 0; i < 4; i++)
      af[i] = *(const bf16x8*)&As[(wr * 64 + i * 16 + ql) * 40 + g * 8];
    #pragma unroll
    for (int i = 0; i < 4; i++)
      bfr[i] = *(const bf16x8*)&Bs[(wc * 64 + i * 16 + ql) * 40 + g * 8];
    #pragma unroll
    for (int i = 0; i < 4; i++)
      #pragma unroll
      for (int j = 0; j < 4; j++)
        acc[i][j] = mfma16(af[i], bfr[j], acc[i][j]);
    __syncthreads();
  }

  #pragma unroll
  for (int i = 0; i < 4; i++) {
    #pragma unroll
    for (int j = 0; j < 4; j++) {
      int col = n0 + wc * 64 + j * 16 + ql;
      #pragma unroll
      for (int r = 0; r < 4; r++) {
        int mrow = m0 + wr * 64 + i * 16 + g * 4 + r;
        float v = acc[i][j][r];
        if (MODE == 0) {
          ((float*)Cp)[(size_t)mrow * N + col] = v + bias[col];
        } else {
          int b = mrow >> 11, nn = mrow & 2047;
          int hh = col >> 6, dd = col & 63;
          size_t base = (size_t)(b * 8 + hh) * 131072;
          if (MODE == 1) ((ushort*)Cp)[base + (size_t)nn * 64 + dd]  = f2bf(v);
          else           ((ushort*)Cp)[base + (size_t)dd * 2048 + nn] = f2bf(v);
        }
      }
    }
  }
}

// ---------------------------------------------------------------- attention
// Fully-transposed 32x32 flash attention with KV-split.
// Q,K: [bh][n][64] bf16; V: [bh][64][n] bf16; mask int32 [b][j].
// S^T = K.Q^T -> lane holds 16 j-vals of one q column; softmax lane-scalar.
// SPLIT>1: each z-block does a 2048/SPLIT j-chunk, writes normalized partial
// O (bf16) + (m, lsum); reduce_k combines.
template<int SPLIT>
__global__ __launch_bounds__(256)
void attn_k(const ushort* __restrict__ Qb, const ushort* __restrict__ Kb,
            const ushort* __restrict__ VT, const int* __restrict__ msk,
            ushort* __restrict__ AO, ushort* __restrict__ Opart,
            float2* __restrict__ Ml)
{
  constexpr int CHUNK = 2048 / SPLIT;
  const int bh = blockIdx.x, b = bh >> 3, h = bh & 7;
  const int sp = (SPLIT > 1) ? blockIdx.z : 0;
  const int jb = sp * CHUNK;
  const int t = threadIdx.x, lane = t & 63, w = t >> 6;
  const int l31 = lane & 31, hi = lane >> 5;
  const int q0 = blockIdx.y * 128 + w * 32;

  const ushort* Qh = Qb + (size_t)bh * 131072;
  const ushort* Kh = Kb + (size_t)bh * 131072;
  const ushort* Vh = VT + (size_t)bh * 131072;
  const int* mp = msk + b * 2048 + 4 * hi;

  bf16x8 qf[4];
  #pragma unroll
  for (int kk = 0; kk < 4; kk++)
    qf[kk] = *(const bf16x8*)(Qh + (size_t)(q0 + l31) * 64 + kk * 16 + 8 * hi);

  f32x16 o0 = {}, o1 = {};
  float m = -1e30f, lsum = 0.f;
  const float sc = 0.18033688011112042f;  // (1/8) * log2(e)

  for (int j0 = jb; j0 < jb + CHUNK; j0 += 32) {
    // ---- mask first (feeds first post-MFMA op; overlaps QK latency)
    int32x4 mv0 = *(const int32x4*)(mp + j0);
    int32x4 mv1 = *(const int32x4*)(mp + j0 + 8);
    int32x4 mv2 = *(const int32x4*)(mp + j0 + 16);
    int32x4 mv3 = *(const int32x4*)(mp + j0 + 24);

    const ushort* kp = Kh + (size_t)(j0 + l31) * 64 + 8 * hi;
    bf16x8 kf0 = *(const bf16x8*)(kp);
    bf16x8 kf1 = *(const bf16x8*)(kp + 16);
    bf16x8 kf2 = *(const bf16x8*)(kp + 32);
    bf16x8 kf3 = *(const bf16x8*)(kp + 48);
    f32x16 z = {};
    f32x16 s = mfma32(kf0, qf[0], z);
    s = mfma32(kf1, qf[1], s);
    s = mfma32(kf2, qf[2], s);
    s = mfma32(kf3, qf[3], s);

    // ---- V loads hoisted above softmax: latency overlaps exp2 work
    const ushort* vp = Vh + (size_t)l31 * 2048 + j0 + 8 * hi;
    bf16x8 vf00 = *(const bf16x8*)(vp);
    bf16x8 vf01 = *(const bf16x8*)(vp + 16);
    bf16x8 vf10 = *(const bf16x8*)(vp + 32 * 2048);
    bf16x8 vf11 = *(const bf16x8*)(vp + 32 * 2048 + 16);

    float pv[16];
    #pragma unroll
    for (int e = 0; e < 4; e++) {
      pv[e]      = mv0[e] ? s[e]      * sc : -1e30f;
      pv[4 + e]  = mv1[e] ? s[4 + e]  * sc : -1e30f;
      pv[8 + e]  = mv2[e] ? s[8 + e]  * sc : -1e30f;
      pv[12 + e] = mv3[e] ? s[12 + e] * sc : -1e30f;
    }

    // ---- max: max3 tree (T17), then one cross-half xor
    float t0 = fmaxf(fmaxf(pv[0],  pv[1]),  pv[2]);
    float t1 = fmaxf(fmaxf(pv[3],  pv[4]),  pv[5]);
    float t2 = fmaxf(fmaxf(pv[6],  pv[7]),  pv[8]);
    float t3 = fmaxf(fmaxf(pv[9],  pv[10]), pv[11]);
    float t4 = fmaxf(fmaxf(pv[12], pv[13]), pv[14]);
    float pm = fmaxf(fmaxf(fmaxf(t0, t1), t2), fmaxf(fmaxf(t3, t4), pv[15]));
    pm = fmaxf(pm, __shfl_xor(pm, 32));

    // ---- defer-max rescale (T13)
    if (!__all(pm <= m + 8.f)) {
      float mn = fmaxf(m, pm);
      float al = exp2f(m - mn);
      lsum *= al;
      #pragma unroll
      for (int r = 0; r < 16; r++) { o0[r] *= al; o1[r] *= al; }
      m = mn;
    }

    #pragma unroll
    for (int r = 0; r < 16; r++) pv[r] = exp2f(pv[r] - m);
    // ---- sum tree
    float a0 = (pv[0] + pv[1]) + (pv[2] + pv[3]);
    float a1 = (pv[4] + pv[5]) + (pv[6] + pv[7]);
    float a2 = (pv[8] + pv[9]) + (pv[10] + pv[11]);
    float a3 = (pv[12] + pv[13]) + (pv[14] + pv[15]);
    float rs = (a0 + a1) + (a2 + a3);
    rs += __shfl_xor(rs, 32);
    lsum += rs;

    // ---- pack P^T into PV B-fragments (8 cvt_pk + 4 permlane32_swap)
    unsigned pk01 = cvtpk(pv[0],  pv[1]),  pk23 = cvtpk(pv[2],  pv[3]);
    unsigned pk45 = cvtpk(pv[4],  pv[5]),  pk67 = cvtpk(pv[6],  pv[7]);
    unsigned pk89 = cvtpk(pv[8],  pv[9]),  pkAB = cvtpk(pv[10], pv[11]);
    unsigned pkCD = cvtpk(pv[12], pv[13]), pkEF = cvtpk(pv[14], pv[15]);
    plswap(pk01, pk45);
    plswap(pk23, pk67);
    plswap(pk89, pkCD);
    plswap(pkAB, pkEF);
    union { unsigned u[4]; bf16x8 v; } pf0, pf1;
    pf0.u[0] = pk01; pf0.u[1] = pk23; pf0.u[2] = pk45; pf0.u[3] = pk67;
    pf1.u[0] = pk89; pf1.u[1] = pkAB; pf1.u[2] = pkCD; pf1.u[3] = pkEF;

    o0 = mfma32(vf00, pf0.v, o0);
    o0 = mfma32(vf01, pf1.v, o0);
    o1 = mfma32(vf10, pf0.v, o1);
    o1 = mfma32(vf11, pf1.v, o1);
  }

  // ---- epilogue: lane holds O^T[d][q] for one q, 32 d-values
  float inv = lsum > 0.f ? 1.0f / lsum : 0.f;
  const int q = q0 + l31;

  if (SPLIT == 1) {
    ushort* aor = AO + ((size_t)(b * 2048 + q)) * 512 + h * 64;
    #pragma unroll
    for (int grp = 0; grp < 4; grp++) {
      int d0 = grp * 8 + 4 * hi;
      uint32x2 w0, w1;
      w0[0] = cvtpk(o0[4 * grp] * inv, o0[4 * grp + 1] * inv);
      w0[1] = cvtpk(o0[4 * grp + 2] * inv, o0[4 * grp + 3] * inv);
      w1[0] = cvtpk(o1[4 * grp] * inv, o1[4 * grp + 1] * inv);
      w1[1] = cvtpk(o1[4 * grp + 2] * inv, o1[4 * grp + 3] * inv);
      *(uint32x2*)(aor + d0)      = w0;
      *(uint32x2*)(aor + 32 + d0) = w1;
    }
  } else {
    ushort* op = Opart + (size_t)sp * 4194304 + ((size_t)(bh * 2048 + q)) * 64;
    #pragma unroll
    for (int grp = 0; grp < 4; grp++) {
      int d0 = grp * 8 + 4 * hi;
      uint32x2 w0, w1;
      w0[0] = cvtpk(o0[4 * grp] * inv, o0[4 * grp + 1] * inv);
      w0[1] = cvtpk(o0[4 * grp + 2] * inv, o0[4 * grp + 3] * inv);
      w1[0] = cvtpk(o1[4 * grp] * inv, o1[4 * grp + 1] * inv);
      w1[1] = cvtpk(o1[4 * grp + 2] * inv, o1[4 * grp + 3] * inv);
      *(uint32x2*)(op + d0)      = w0;
      *(uint32x2*)(op + 32 + d0) = w1;
    }
    if (hi == 0) {
      float2 v; v.x = m; v.y = lsum;
      Ml[sp * 65536 + bh * 2048 + q] = v;
    }
  }
}

// Combine SPLIT=4 partials: AO[bh,q,:] = sum_s w_s * Opart_s[bh,q,:]
__global__ __launch_bounds__(256)
void reduce_k(const ushort* __restrict__ Opart, const float2* __restrict__ Ml,
              ushort* __restrict__ AO)
{
  const int idx = blockIdx.x * 256 + threadIdx.x;   // 524288 total
  const int d8 = idx & 7, q = (idx >> 3) & 2047, bh = idx >> 14;
  const int b = bh >> 3, h = bh & 7;

  float2 ml[4];
  float M = -1e30f;
  #pragma unroll
  for (int s = 0; s < 4; s++) {
    ml[s] = Ml[s * 65536 + bh * 2048 + q];
    M = fmaxf(M, ml[s].x);
  }
  float wgt[4], L = 0.f;
  #pragma unroll
  for (int s = 0; s < 4; s++) {
    wgt[s] = ml[s].y * exp2f(ml[s].x - M);
    L += wgt[s];
  }
  float invL = 1.f / L;

  float acc[8] = {0.f,0.f,0.f,0.f,0.f,0.f,0.f,0.f};
  #pragma unroll
  for (int s = 0; s < 4; s++) {
    bf16x8 v = *(const bf16x8*)(Opart + (size_t)s * 4194304 +
                                ((size_t)(bh * 2048 + q)) * 64 + d8 * 8);
    float ws = wgt[s] * invL;
    #pragma unroll
    for (int e = 0; e < 8; e++) acc[e] += ws * bf2f(v[e]);
  }

  union { unsigned u[4]; int32x4 v; } pk;
  pk.u[0] = cvtpk(acc[0], acc[1]);
  pk.u[1] = cvtpk(acc[2], acc[3]);
  pk.u[2] = cvtpk(acc[4], acc[5]);
  pk.u[3] = cvtpk(acc[6], acc[7]);
  *(int32x4*)(AO + ((size_t)(b * 2048 + q)) * 512 + h * 64 + d8 * 8) = pk.v;
}

extern "C" void kernel_launch(void* const* d_in, const int* in_sizes, int n_in,
                              void* d_out, int out_size, void* d_ws, size_t ws_size,
                              hipStream_t stream)
{
  const float* x   = (const float*)d_in[0];
  const float* ctx = (const float*)d_in[1];
  const int*   mk  = (const int*)d_in[2];
  const float* Wq  = (const float*)d_in[3];
  const float* Wk  = (const float*)d_in[4];
  const float* Wv  = (const float*)d_in[5];
  const float* Wo  = (const float*)d_in[6];
  const float* bo  = (const float*)d_in[7];
  float* out = (float*)d_out;

  ushort* Qb    = (ushort*)d_ws;          // 8 MB  [32][2048][64]
  ushort* Kb    = Qb + 4194304;           // 8 MB
  ushort* VT    = Kb + 4194304;           // 8 MB  [32][64][2048]
  ushort* AO    = VT + 4194304;           // 8 MB
  ushort* Opart = AO + 4194304;           // 32 MB (4 splits x 8 MB)
  float2* Ml    = (float2*)(Qb + 33554432); // 2 MB (4 x 32 x 2048 x float2)
  const size_t WS_NEED = 69206016;        // 66 MB + 2 MB

  gemm_k<false, 1><<<dim3(4, 64), 256, 0, stream>>>(x,   Wq, Qb, nullptr, 8192, 512, 1024);
  gemm_k<false, 1><<<dim3(4, 64), 256, 0, stream>>>(ctx, Wk, Kb, nullptr, 8192, 512, 768);
  gemm_k<false, 2><<<dim3(4, 64), 256, 0, stream>>>(ctx, Wv, VT, nullptr, 8192, 512, 768);

  if (ws_size >= WS_NEED) {
    attn_k<4><<<dim3(32, 16, 4), 256, 0, stream>>>(Qb, Kb, VT, mk, AO, Opart, Ml);
    reduce_k<<<2048, 256, 0, stream>>>(Opart, Ml, AO);
  } else {
    attn_k<1><<<dim3(32, 16, 1), 256, 0, stream>>>(Qb, Kb, VT, mk, AO, Opart, Ml);
  }

  gemm_k<true, 0><<<dim3(8, 64), 256, 0, stream>>>(AO, Wo, out, bo, 8192, 1024, 512);
}

// Round 4
// 236.197 us; speedup vs baseline: 1.2698x; 1.2698x over previous
//
#include <hip/hip_runtime.h>
#include <hip/hip_bf16.h>

typedef __attribute__((ext_vector_type(4)))  float  f32x4;
typedef __attribute__((ext_vector_type(16))) float  f32x16;
typedef __attribute__((ext_vector_type(8)))  short  bf16x8;
typedef __attribute__((ext_vector_type(4)))  int    int32x4;
typedef __attribute__((ext_vector_type(2)))  unsigned int uint32x2;

#define DEVINL static __device__ __forceinline__
#define GAS __attribute__((address_space(1)))
#define LAS __attribute__((address_space(3)))

DEVINL ushort f2bf(float f) {
  unsigned u = __builtin_bit_cast(unsigned, f);
  unsigned r = u + 0x7fffu + ((u >> 16) & 1u);
  return (ushort)(r >> 16);
}

DEVINL unsigned cvtpk(float lo, float hi) {
  unsigned r;
  asm("v_cvt_pk_bf16_f32 %0, %1, %2" : "=v"(r) : "v"(lo), "v"(hi));
  return r;
}

DEVINL void plswap(unsigned &a, unsigned &b) {
  asm("v_permlane32_swap_b32 %0, %1" : "+v"(a), "+v"(b));
}

DEVINL float bf2f(short s) {
  return __builtin_bit_cast(float, ((unsigned)(ushort)s) << 16);
}

DEVINL f32x4 mfma16(bf16x8 a, bf16x8 b, f32x4 c) {
  return __builtin_amdgcn_mfma_f32_16x16x32_bf16(a, b, c, 0, 0, 0);
}
DEVINL f32x16 mfma32(bf16x8 a, bf16x8 b, f32x16 c) {
  return __builtin_amdgcn_mfma_f32_32x32x16_bf16(a, b, c, 0, 0, 0);
}

// ---------------------------------------------------------------- GEMM
// C = A @ B.  A [M,K] (f32 or bf16), B [K,N] f32 (cast to bf16 in staging).
// MODE 0: C f32 [M,N] + bias
// MODE 1: C bf16 scattered to [b,h,n,d]
// MODE 2: C bf16 scattered to [b,h,d,n]  (V transposed)
template<bool ABF, int MODE>
__global__ __launch_bounds__(256)
void gemm_k(const void* __restrict__ Ap, const float* __restrict__ Bp,
            void* __restrict__ Cp, const float* __restrict__ bias,
            int M, int N, int K)
{
  __shared__ ushort As[128 * 40];
  __shared__ ushort Bs[128 * 40];
  const int t  = threadIdx.x;
  const int m0 = blockIdx.y * 128, n0 = blockIdx.x * 128;
  const int lane = t & 63, w = t >> 6;
  const int wr = w >> 1, wc = w & 1;
  const int g = lane >> 4, ql = lane & 15;

  const int arow = t >> 1, akc = (t & 1) * 16;
  const int bgr = t >> 5, blc = (t & 31) * 4;

  f32x4 acc[4][4];
  #pragma unroll
  for (int i = 0; i < 4; i++)
    #pragma unroll
    for (int j = 0; j < 4; j++) acc[i][j] = (f32x4){0.f, 0.f, 0.f, 0.f};

  for (int k0 = 0; k0 < K; k0 += 32) {
    {
      ushort* dst = &As[arow * 40 + akc];
      if (ABF) {
        const ushort* ap = (const ushort*)Ap + (size_t)(m0 + arow) * K + k0 + akc;
        *(bf16x8*)dst       = *(const bf16x8*)ap;
        *(bf16x8*)(dst + 8) = *(const bf16x8*)(ap + 8);
      } else {
        const float* ap = (const float*)Ap + (size_t)(m0 + arow) * K + k0 + akc;
        f32x4 v0 = *(const f32x4*)(ap + 0);
        f32x4 v1 = *(const f32x4*)(ap + 4);
        f32x4 v2 = *(const f32x4*)(ap + 8);
        f32x4 v3 = *(const f32x4*)(ap + 12);
        bf16x8 h0, h1;
        #pragma unroll
        for (int i = 0; i < 4; i++) {
          h0[i]     = (short)f2bf(v0[i]);
          h0[i + 4] = (short)f2bf(v1[i]);
          h1[i]     = (short)f2bf(v2[i]);
          h1[i + 4] = (short)f2bf(v3[i]);
        }
        *(bf16x8*)dst       = h0;
        *(bf16x8*)(dst + 8) = h1;
      }
    }
    {
      const float* bp = Bp + (size_t)(k0 + bgr * 4) * N + n0 + blc;
      f32x4 r0 = *(const f32x4*)(bp);
      f32x4 r1 = *(const f32x4*)(bp + N);
      f32x4 r2 = *(const f32x4*)(bp + 2 * N);
      f32x4 r3 = *(const f32x4*)(bp + 3 * N);
      #pragma unroll
      for (int j = 0; j < 4; j++) {
        uint32x2 pr;
        pr[0] = ((unsigned)f2bf(r1[j]) << 16) | f2bf(r0[j]);
        pr[1] = ((unsigned)f2bf(r3[j]) << 16) | f2bf(r2[j]);
        *(uint32x2*)&Bs[(blc + j) * 40 + bgr * 4] = pr;
      }
    }
    __syncthreads();

    bf16x8 af[4], bfr[4];
    #pragma unroll
    for (int i = 0; i < 4; i++)
      af[i] = *(const bf16x8*)&As[(wr * 64 + i * 16 + ql) * 40 + g * 8];
    #pragma unroll
    for (int i = 0; i < 4; i++)
      bfr[i] = *(const bf16x8*)&Bs[(wc * 64 + i * 16 + ql) * 40 + g * 8];
    #pragma unroll
    for (int i = 0; i < 4; i++)
      #pragma unroll
      for (int j = 0; j < 4; j++)
        acc[i][j] = mfma16(af[i], bfr[j], acc[i][j]);
    __syncthreads();
  }

  #pragma unroll
  for (int i = 0; i < 4; i++) {
    #pragma unroll
    for (int j = 0; j < 4; j++) {
      int col = n0 + wc * 64 + j * 16 + ql;
      #pragma unroll
      for (int r = 0; r < 4; r++) {
        int mrow = m0 + wr * 64 + i * 16 + g * 4 + r;
        float v = acc[i][j][r];
        if (MODE == 0) {
          ((float*)Cp)[(size_t)mrow * N + col] = v + bias[col];
        } else {
          int b = mrow >> 11, nn = mrow & 2047;
          int hh = col >> 6, dd = col & 63;
          size_t base = (size_t)(b * 8 + hh) * 131072;
          if (MODE == 1) ((ushort*)Cp)[base + (size_t)nn * 64 + dd]  = f2bf(v);
          else           ((ushort*)Cp)[base + (size_t)dd * 2048 + nn] = f2bf(v);
        }
      }
    }
  }
}

// ---------------------------------------------------------------- attention
// Fully-transposed 32x32 flash attention, KV-split, LDS-staged double-buffered
// K/V tiles prefetched one tile ahead via global_load_lds DMA.
// Q,K: [bh][n][64] bf16; V: [bh][64][n] bf16 (transposed); mask int32 [b][j].
// KVBLK=64 per tile, 2 j-subtiles of 32.  LDS tiles [64 rows][64 cols] bf16,
// linear dest (gload_lds requirement) + XOR swizzle byte^=(row&7)<<4 applied
// to the GLOBAL source at stage time and the ds_read address at consume time
// (rule 21: both-sides-or-neither).
template<int SPLIT>
__global__ __launch_bounds__(256)
void attn_k(const ushort* __restrict__ Qb, const ushort* __restrict__ Kb,
            const ushort* __restrict__ VT, const int* __restrict__ msk,
            ushort* __restrict__ AO, ushort* __restrict__ Opart,
            float2* __restrict__ Ml)
{
  constexpr int CHUNK = 2048 / SPLIT;
  constexpr int NT = CHUNK / 64;
  __shared__ ushort Ks[2][64 * 64];
  __shared__ ushort Vs[2][64 * 64];

  const int bh = blockIdx.x, b = bh >> 3, h = bh & 7;
  const int sp = (SPLIT > 1) ? blockIdx.z : 0;
  const int jb = sp * CHUNK;
  const int t = threadIdx.x, lane = t & 63, w = t >> 6;
  const int l31 = lane & 31, hi = lane >> 5;
  const int q0 = blockIdx.y * 128 + w * 32;

  const ushort* Qh = Qb + (size_t)bh * 131072;
  const ushort* Kh = Kb + (size_t)bh * 131072;
  const ushort* Vh = VT + (size_t)bh * 131072;
  const int* mp = msk + b * 2048 + 4 * hi;

  // staging lane params: each wave stages 16 K-rows and 16 V-rows per tile.
  const int srow = lane >> 3;              // 0..7 within an 8-row chunk
  const int soff = ((lane & 7) * 16) ^ ((srow & 7) << 4);  // swizzled byte in row

  auto stage = [&](int buf, int j0) {
    const char* kg = (const char*)Kh + ((size_t)(j0 + 16 * w + srow)) * 128 + soff;
    __builtin_amdgcn_global_load_lds((const GAS void*)kg,
        (LAS void*)&Ks[buf][16 * w * 64], 16, 0, 0);
    __builtin_amdgcn_global_load_lds((const GAS void*)(kg + 1024),
        (LAS void*)&Ks[buf][(16 * w + 8) * 64], 16, 0, 0);
    const char* vg = (const char*)Vh + ((size_t)(16 * w + srow)) * 4096 + (size_t)j0 * 2 + soff;
    __builtin_amdgcn_global_load_lds((const GAS void*)vg,
        (LAS void*)&Vs[buf][16 * w * 64], 16, 0, 0);
    __builtin_amdgcn_global_load_lds((const GAS void*)(vg + 8 * 4096),
        (LAS void*)&Vs[buf][(16 * w + 8) * 64], 16, 0, 0);
  };

  bf16x8 qf[4];
  #pragma unroll
  for (int kk = 0; kk < 4; kk++)
    qf[kk] = *(const bf16x8*)(Qh + (size_t)(q0 + l31) * 64 + kk * 16 + 8 * hi);

  f32x16 o0 = {}, o1 = {};
  float m = -1e30f, lsum = 0.f;
  const float sc = 0.18033688011112042f;  // (1/8) * log2(e)

  stage(0, jb);
  __syncthreads();

  for (int tt = 0; tt < NT; ++tt) {
    const int cur = tt & 1;
    if (tt + 1 < NT) stage(cur ^ 1, jb + (tt + 1) * 64);

    #pragma unroll
    for (int js = 0; js < 2; ++js) {
      const int jloc = js * 32;
      const int j0 = jb + tt * 64 + jloc;   // global j of this subtile

      int32x4 mv0 = *(const int32x4*)(mp + j0);
      int32x4 mv1 = *(const int32x4*)(mp + j0 + 8);
      int32x4 mv2 = *(const int32x4*)(mp + j0 + 16);
      int32x4 mv3 = *(const int32x4*)(mp + j0 + 24);

      // ---- K fragments from LDS (swizzled read)
      const int krow = jloc + l31;
      const unsigned rsw = (unsigned)((l31 & 7) << 4);
      const char* kbase = (const char*)&Ks[cur][0] + krow * 128;
      bf16x8 kf0 = *(const bf16x8*)(kbase + ((0  + hi * 16) ^ rsw));
      bf16x8 kf1 = *(const bf16x8*)(kbase + ((32 + hi * 16) ^ rsw));
      bf16x8 kf2 = *(const bf16x8*)(kbase + ((64 + hi * 16) ^ rsw));
      bf16x8 kf3 = *(const bf16x8*)(kbase + ((96 + hi * 16) ^ rsw));

      f32x16 z = {};
      f32x16 s = mfma32(kf0, qf[0], z);
      s = mfma32(kf1, qf[1], s);
      s = mfma32(kf2, qf[2], s);
      s = mfma32(kf3, qf[3], s);

      // ---- V fragments from LDS (rows l31 and l31+32; same row&7 -> same swz)
      const char* vb0 = (const char*)&Vs[cur][0] + l31 * 128;
      const char* vb1 = vb0 + 32 * 128;
      const unsigned vc0 = (unsigned)((jloc * 2 + hi * 16) ^ rsw);
      const unsigned vc1 = (unsigned)((jloc * 2 + 32 + hi * 16) ^ rsw);
      bf16x8 vf00 = *(const bf16x8*)(vb0 + vc0);
      bf16x8 vf01 = *(const bf16x8*)(vb0 + vc1);
      bf16x8 vf10 = *(const bf16x8*)(vb1 + vc0);
      bf16x8 vf11 = *(const bf16x8*)(vb1 + vc1);

      float pv[16];
      #pragma unroll
      for (int e = 0; e < 4; e++) {
        pv[e]      = mv0[e] ? s[e]      * sc : -1e30f;
        pv[4 + e]  = mv1[e] ? s[4 + e]  * sc : -1e30f;
        pv[8 + e]  = mv2[e] ? s[8 + e]  * sc : -1e30f;
        pv[12 + e] = mv3[e] ? s[12 + e] * sc : -1e30f;
      }

      float t0 = fmaxf(fmaxf(pv[0],  pv[1]),  pv[2]);
      float t1 = fmaxf(fmaxf(pv[3],  pv[4]),  pv[5]);
      float t2 = fmaxf(fmaxf(pv[6],  pv[7]),  pv[8]);
      float t3 = fmaxf(fmaxf(pv[9],  pv[10]), pv[11]);
      float t4 = fmaxf(fmaxf(pv[12], pv[13]), pv[14]);
      float pm = fmaxf(fmaxf(fmaxf(t0, t1), t2), fmaxf(fmaxf(t3, t4), pv[15]));
      pm = fmaxf(pm, __shfl_xor(pm, 32));

      if (!__all(pm <= m + 8.f)) {
        float mn = fmaxf(m, pm);
        float al = exp2f(m - mn);
        lsum *= al;
        #pragma unroll
        for (int r = 0; r < 16; r++) { o0[r] *= al; o1[r] *= al; }
        m = mn;
      }

      #pragma unroll
      for (int r = 0; r < 16; r++) pv[r] = exp2f(pv[r] - m);
      float a0 = (pv[0] + pv[1]) + (pv[2] + pv[3]);
      float a1 = (pv[4] + pv[5]) + (pv[6] + pv[7]);
      float a2 = (pv[8] + pv[9]) + (pv[10] + pv[11]);
      float a3 = (pv[12] + pv[13]) + (pv[14] + pv[15]);
      float rs = (a0 + a1) + (a2 + a3);
      rs += __shfl_xor(rs, 32);
      lsum += rs;

      unsigned pk01 = cvtpk(pv[0],  pv[1]),  pk23 = cvtpk(pv[2],  pv[3]);
      unsigned pk45 = cvtpk(pv[4],  pv[5]),  pk67 = cvtpk(pv[6],  pv[7]);
      unsigned pk89 = cvtpk(pv[8],  pv[9]),  pkAB = cvtpk(pv[10], pv[11]);
      unsigned pkCD = cvtpk(pv[12], pv[13]), pkEF = cvtpk(pv[14], pv[15]);
      plswap(pk01, pk45);
      plswap(pk23, pk67);
      plswap(pk89, pkCD);
      plswap(pkAB, pkEF);
      union { unsigned u[4]; bf16x8 v; } pf0, pf1;
      pf0.u[0] = pk01; pf0.u[1] = pk23; pf0.u[2] = pk45; pf0.u[3] = pk67;
      pf1.u[0] = pk89; pf1.u[1] = pkAB; pf1.u[2] = pkCD; pf1.u[3] = pkEF;

      o0 = mfma32(vf00, pf0.v, o0);
      o0 = mfma32(vf01, pf1.v, o0);
      o1 = mfma32(vf10, pf0.v, o1);
      o1 = mfma32(vf11, pf1.v, o1);
    }
    __syncthreads();   // DMA for tt+1 landed; all reads of buf cur done
  }

  // ---- epilogue: lane holds O^T[d][q] for one q, 32 d-values
  float inv = lsum > 0.f ? 1.0f / lsum : 0.f;
  const int q = q0 + l31;

  if (SPLIT == 1) {
    ushort* aor = AO + ((size_t)(b * 2048 + q)) * 512 + h * 64;
    #pragma unroll
    for (int grp = 0; grp < 4; grp++) {
      int d0 = grp * 8 + 4 * hi;
      uint32x2 w0, w1;
      w0[0] = cvtpk(o0[4 * grp] * inv, o0[4 * grp + 1] * inv);
      w0[1] = cvtpk(o0[4 * grp + 2] * inv, o0[4 * grp + 3] * inv);
      w1[0] = cvtpk(o1[4 * grp] * inv, o1[4 * grp + 1] * inv);
      w1[1] = cvtpk(o1[4 * grp + 2] * inv, o1[4 * grp + 3] * inv);
      *(uint32x2*)(aor + d0)      = w0;
      *(uint32x2*)(aor + 32 + d0) = w1;
    }
  } else {
    ushort* op = Opart + (size_t)sp * 4194304 + ((size_t)(bh * 2048 + q)) * 64;
    #pragma unroll
    for (int grp = 0; grp < 4; grp++) {
      int d0 = grp * 8 + 4 * hi;
      uint32x2 w0, w1;
      w0[0] = cvtpk(o0[4 * grp] * inv, o0[4 * grp + 1] * inv);
      w0[1] = cvtpk(o0[4 * grp + 2] * inv, o0[4 * grp + 3] * inv);
      w1[0] = cvtpk(o1[4 * grp] * inv, o1[4 * grp + 1] * inv);
      w1[1] = cvtpk(o1[4 * grp + 2] * inv, o1[4 * grp + 3] * inv);
      *(uint32x2*)(op + d0)      = w0;
      *(uint32x2*)(op + 32 + d0) = w1;
    }
    if (hi == 0) {
      float2 v; v.x = m; v.y = lsum;
      Ml[sp * 65536 + bh * 2048 + q] = v;
    }
  }
}

// Combine SPLIT=4 partials: AO[bh,q,:] = sum_s w_s * Opart_s[bh,q,:]
__global__ __launch_bounds__(256)
void reduce_k(const ushort* __restrict__ Opart, const float2* __restrict__ Ml,
              ushort* __restrict__ AO)
{
  const int idx = blockIdx.x * 256 + threadIdx.x;   // 524288 total
  const int d8 = idx & 7, q = (idx >> 3) & 2047, bh = idx >> 14;
  const int b = bh >> 3, h = bh & 7;

  float2 ml[4];
  float M = -1e30f;
  #pragma unroll
  for (int s = 0; s < 4; s++) {
    ml[s] = Ml[s * 65536 + bh * 2048 + q];
    M = fmaxf(M, ml[s].x);
  }
  float wgt[4], L = 0.f;
  #pragma unroll
  for (int s = 0; s < 4; s++) {
    wgt[s] = ml[s].y * exp2f(ml[s].x - M);
    L += wgt[s];
  }
  float invL = 1.f / L;

  float acc[8] = {0.f,0.f,0.f,0.f,0.f,0.f,0.f,0.f};
  #pragma unroll
  for (int s = 0; s < 4; s++) {
    bf16x8 v = *(const bf16x8*)(Opart + (size_t)s * 4194304 +
                                ((size_t)(bh * 2048 + q)) * 64 + d8 * 8);
    float ws = wgt[s] * invL;
    #pragma unroll
    for (int e = 0; e < 8; e++) acc[e] += ws * bf2f(v[e]);
  }

  union { unsigned u[4]; int32x4 v; } pk;
  pk.u[0] = cvtpk(acc[0], acc[1]);
  pk.u[1] = cvtpk(acc[2], acc[3]);
  pk.u[2] = cvtpk(acc[4], acc[5]);
  pk.u[3] = cvtpk(acc[6], acc[7]);
  *(int32x4*)(AO + ((size_t)(b * 2048 + q)) * 512 + h * 64 + d8 * 8) = pk.v;
}

extern "C" void kernel_launch(void* const* d_in, const int* in_sizes, int n_in,
                              void* d_out, int out_size, void* d_ws, size_t ws_size,
                              hipStream_t stream)
{
  const float* x   = (const float*)d_in[0];
  const float* ctx = (const float*)d_in[1];
  const int*   mk  = (const int*)d_in[2];
  const float* Wq  = (const float*)d_in[3];
  const float* Wk  = (const float*)d_in[4];
  const float* Wv  = (const float*)d_in[5];
  const float* Wo  = (const float*)d_in[6];
  const float* bo  = (const float*)d_in[7];
  float* out = (float*)d_out;

  ushort* Qb    = (ushort*)d_ws;          // 8 MB  [32][2048][64]
  ushort* Kb    = Qb + 4194304;           // 8 MB
  ushort* VT    = Kb + 4194304;           // 8 MB  [32][64][2048]
  ushort* AO    = VT + 4194304;           // 8 MB
  ushort* Opart = AO + 4194304;           // 32 MB (4 splits x 8 MB)
  float2* Ml    = (float2*)(Qb + 33554432); // 2 MB
  const size_t WS_NEED = 69206016;

  gemm_k<false, 1><<<dim3(4, 64), 256, 0, stream>>>(x,   Wq, Qb, nullptr, 8192, 512, 1024);
  gemm_k<false, 1><<<dim3(4, 64), 256, 0, stream>>>(ctx, Wk, Kb, nullptr, 8192, 512, 768);
  gemm_k<false, 2><<<dim3(4, 64), 256, 0, stream>>>(ctx, Wv, VT, nullptr, 8192, 512, 768);

  if (ws_size >= WS_NEED) {
    attn_k<4><<<dim3(32, 16, 4), 256, 0, stream>>>(Qb, Kb, VT, mk, AO, Opart, Ml);
    reduce_k<<<2048, 256, 0, stream>>>(Opart, Ml, AO);
  } else {
    attn_k<1><<<dim3(32, 16, 1), 256, 0, stream>>>(Qb, Kb, VT, mk, AO, Opart, Ml);
  }

  gemm_k<true, 0><<<dim3(8, 64), 256, 0, stream>>>(AO, Wo, out, bo, 8192, 1024, 512);
}

// Round 5
// 167.610 us; speedup vs baseline: 1.7895x; 1.4092x over previous
//
#include <hip/hip_runtime.h>
#include <hip/hip_bf16.h>

typedef __attribute__((ext_vector_type(4)))  float  f32x4;
typedef __attribute__((ext_vector_type(16))) float  f32x16;
typedef __attribute__((ext_vector_type(8)))  short  bf16x8;
typedef __attribute__((ext_vector_type(4)))  int    int32x4;
typedef __attribute__((ext_vector_type(2)))  unsigned int uint32x2;

#define DEVINL static __device__ __forceinline__
#define GAS __attribute__((address_space(1)))
#define LAS __attribute__((address_space(3)))

DEVINL ushort f2bf(float f) {
  unsigned u = __builtin_bit_cast(unsigned, f);
  unsigned r = u + 0x7fffu + ((u >> 16) & 1u);
  return (ushort)(r >> 16);
}

DEVINL unsigned cvtpk(float lo, float hi) {
  unsigned r;
  asm("v_cvt_pk_bf16_f32 %0, %1, %2" : "=v"(r) : "v"(lo), "v"(hi));
  return r;
}

DEVINL void plswap(unsigned &a, unsigned &b) {
  asm("v_permlane32_swap_b32 %0, %1" : "+v"(a), "+v"(b));
}

DEVINL float bf2f(short s) {
  return __builtin_bit_cast(float, ((unsigned)(ushort)s) << 16);
}

DEVINL f32x4 mfma16(bf16x8 a, bf16x8 b, f32x4 c) {
  return __builtin_amdgcn_mfma_f32_16x16x32_bf16(a, b, c, 0, 0, 0);
}
DEVINL f32x16 mfma32(bf16x8 a, bf16x8 b, f32x16 c) {
  return __builtin_amdgcn_mfma_f32_32x32x16_bf16(a, b, c, 0, 0, 0);
}

// ------------------------------------------------------------ pre-pass: f32 -> bf16
__global__ __launch_bounds__(256)
void cvt_k(const float* __restrict__ x, const float* __restrict__ ctx,
           ushort* __restrict__ xb, ushort* __restrict__ cb)
{
  const int NX = 8388608, NC = 6291456;          // elems
  int tid = blockIdx.x * 256 + threadIdx.x;
  for (int i = tid; i < (NX + NC) / 8; i += 2048 * 256) {
    int e = i * 8;
    const float* s; ushort* d;
    if (e < NX) { s = x + e; d = xb + e; }
    else        { s = ctx + (e - NX); d = cb + (e - NX); }
    f32x4 v0 = *(const f32x4*)s;
    f32x4 v1 = *(const f32x4*)(s + 4);
    union { unsigned u[4]; int32x4 v; } pk;
    pk.u[0] = cvtpk(v0[0], v0[1]);
    pk.u[1] = cvtpk(v0[2], v0[3]);
    pk.u[2] = cvtpk(v1[0], v1[1]);
    pk.u[3] = cvtpk(v1[2], v1[3]);
    *(int32x4*)d = pk.v;
  }
}

// ------------------------------------------------------------ pre-pass: W [K][N] f32 -> W^T [N][K] bf16
__global__ __launch_bounds__(256)
void wtcvt_k(const float* __restrict__ Wq, const float* __restrict__ Wk,
             const float* __restrict__ Wv, const float* __restrict__ Wo,
             ushort* __restrict__ WqT, ushort* __restrict__ WkT,
             ushort* __restrict__ WvT, ushort* __restrict__ WoT)
{
  __shared__ ushort Ts[64][72];
  int id = blockIdx.x;
  const float* src; ushort* dst; int Kd, Nd, lid;
  if (id < 128)      { src = Wq; dst = WqT; Kd = 1024; Nd = 512;  lid = id; }
  else if (id < 224) { src = Wk; dst = WkT; Kd = 768;  Nd = 512;  lid = id - 128; }
  else if (id < 320) { src = Wv; dst = WvT; Kd = 768;  Nd = 512;  lid = id - 224; }
  else               { src = Wo; dst = WoT; Kd = 512;  Nd = 1024; lid = id - 320; }
  const int sh = (Nd == 512) ? 3 : 4;            // Nd/64 = 8 or 16
  const int kb = lid >> sh, nb = lid & ((1 << sh) - 1);
  const int k0 = kb * 64, n0 = nb * 64;
  const int t = threadIdx.x;
  const int r = t >> 2, c0 = (t & 3) * 16;

  const float* sp = src + (size_t)(k0 + r) * Nd + n0 + c0;
  f32x4 v0 = *(const f32x4*)(sp);
  f32x4 v1 = *(const f32x4*)(sp + 4);
  f32x4 v2 = *(const f32x4*)(sp + 8);
  f32x4 v3 = *(const f32x4*)(sp + 12);
  #pragma unroll
  for (int e = 0; e < 4; e++) {
    Ts[c0 + e][r]      = f2bf(v0[e]);
    Ts[c0 + 4 + e][r]  = f2bf(v1[e]);
    Ts[c0 + 8 + e][r]  = f2bf(v2[e]);
    Ts[c0 + 12 + e][r] = f2bf(v3[e]);
  }
  __syncthreads();
  const int n = t >> 2, kc = (t & 3) * 16;
  bf16x8 o0 = *(const bf16x8*)&Ts[n][kc];
  bf16x8 o1 = *(const bf16x8*)&Ts[n][kc + 8];
  ushort* dp = dst + (size_t)(n0 + n) * Kd + k0 + kc;
  *(bf16x8*)dp       = o0;
  *(bf16x8*)(dp + 8) = o1;
}

// ------------------------------------------------------------ GEMM (m97 structure)
// A [M,K] bf16, BT [N,K] bf16.  128x128 tile, BK=32, 4 waves, dbuf LDS via
// global_load_lds w=16.  XOR swizzle: LDS granule = g ^ ((row>>1)&3), applied
// inverse on the global SOURCE at stage, and on the ds_read address (rule 21).
// PHASE 0: fused QKV, 768 blocks (id>>8 selects job), MODE 1/2 bf16 scatter.
// PHASE 1: out-proj, 512 blocks, f32 [M,1024] + bias.
template<int PHASE>
__global__ __launch_bounds__(256)
void mm_k(const ushort* __restrict__ xb, const ushort* __restrict__ cb,
          const ushort* __restrict__ WqT, const ushort* __restrict__ WkT,
          const ushort* __restrict__ WvT,
          ushort* __restrict__ Qb, ushort* __restrict__ Kb, ushort* __restrict__ VT,
          const ushort* __restrict__ AO, const ushort* __restrict__ WoT,
          float* __restrict__ out, const float* __restrict__ bias)
{
  __shared__ ushort As[2][128 * 32];
  __shared__ ushort Bs[2][128 * 32];

  const ushort* A; const ushort* BT; ushort* Cw = nullptr;
  int Kd, mode, m0, n0;
  if (PHASE == 0) {
    int id = blockIdx.x;
    id = (id & 7) * 96 + (id >> 3);              // XCD swizzle (768 % 8 == 0)
    const int which = id >> 8, local = id & 255;
    m0 = (local >> 2) * 128; n0 = (local & 3) * 128;
    if (which == 0)      { A = xb; BT = WqT; Cw = Qb; Kd = 1024; mode = 1; }
    else if (which == 1) { A = cb; BT = WkT; Cw = Kb; Kd = 768;  mode = 1; }
    else                 { A = cb; BT = WvT; Cw = VT; Kd = 768;  mode = 2; }
  } else {
    int id = blockIdx.x;
    id = (id & 7) * 64 + (id >> 3);              // 512 % 8 == 0
    m0 = (id >> 3) * 128; n0 = (id & 7) * 128;
    A = AO; BT = WoT; Kd = 512; mode = 0;
  }

  const int t = threadIdx.x, lane = t & 63, w = t >> 6;
  const int wr = w >> 1, wc = w & 1;
  const int g = lane >> 4, ql = lane & 15;

  // stage lane params: row = i*64 + 16w + (lane>>2), dest linear lane*16B
  const int srowo = 16 * w + (lane >> 2);
  const int sgg = (lane & 3) ^ ((lane >> 3) & 3); // (row>>1)&3 == (lane>>3)&3

  f32x4 acc[4][4];
  #pragma unroll
  for (int i = 0; i < 4; i++)
    #pragma unroll
    for (int j = 0; j < 4; j++) acc[i][j] = (f32x4){0.f, 0.f, 0.f, 0.f};

  auto stage = [&](int buf, int k0) {
    #pragma unroll
    for (int i = 0; i < 2; i++) {
      const int row = i * 64 + srowo;
      const ushort* asrc = A + (size_t)(m0 + row) * Kd + k0 + sgg * 8;
      __builtin_amdgcn_global_load_lds((const GAS void*)asrc,
          (LAS void*)&As[buf][(i * 64 + 16 * w) * 32], 16, 0, 0);
      const ushort* bsrc = BT + (size_t)(n0 + row) * Kd + k0 + sgg * 8;
      __builtin_amdgcn_global_load_lds((const GAS void*)bsrc,
          (LAS void*)&Bs[buf][(i * 64 + 16 * w) * 32], 16, 0, 0);
    }
  };

  const int NK = Kd >> 5;
  stage(0, 0);
  __syncthreads();

  const int sel = (ql >> 1) & 3;                 // (row>>1)&3 for all fragment rows
  const int koff = (g ^ sel) * 8;

  for (int tt = 0; tt < NK; tt++) {
    const int cur = tt & 1;
    if (tt + 1 < NK) stage(cur ^ 1, (tt + 1) * 32);

    bf16x8 af[4], bfr[4];
    #pragma unroll
    for (int i = 0; i < 4; i++) {
      af[i]  = *(const bf16x8*)&As[cur][(wr * 64 + i * 16 + ql) * 32 + koff];
      bfr[i] = *(const bf16x8*)&Bs[cur][(wc * 64 + i * 16 + ql) * 32 + koff];
    }
    #pragma unroll
    for (int i = 0; i < 4; i++)
      #pragma unroll
      for (int j = 0; j < 4; j++)
        acc[i][j] = mfma16(af[i], bfr[j], acc[i][j]);
    __syncthreads();
  }

  // epilogue.  D: row = 4*(lane>>4)+r, col = lane&15
  #pragma unroll
  for (int i = 0; i < 4; i++) {
    #pragma unroll
    for (int j = 0; j < 4; j++) {
      int col = n0 + wc * 64 + j * 16 + ql;
      #pragma unroll
      for (int r = 0; r < 4; r++) {
        int mrow = m0 + wr * 64 + i * 16 + g * 4 + r;
        float v = acc[i][j][r];
        if (PHASE == 1) {
          out[(size_t)mrow * 1024 + col] = v + bias[col];
        } else {
          int b = mrow >> 11, nn = mrow & 2047;
          int hh = col >> 6, dd = col & 63;
          size_t base = (size_t)(b * 8 + hh) * 131072;
          if (mode == 1) Cw[base + (size_t)nn * 64 + dd]   = f2bf(v);
          else           Cw[base + (size_t)dd * 2048 + nn] = f2bf(v);
        }
      }
    }
  }
}

// ------------------------------------------------------------ attention (unchanged structure)
// Fully-transposed 32x32 flash attention, KV-split=4, LDS-staged dbuf K/V via
// global_load_lds, XOR swizzle byte^=(row&7)<<4 on source + read.
__global__ __launch_bounds__(256)
void attn_k(const ushort* __restrict__ Qb, const ushort* __restrict__ Kb,
            const ushort* __restrict__ VT, const int* __restrict__ msk,
            ushort* __restrict__ Opart, float2* __restrict__ Ml)
{
  constexpr int CHUNK = 512, NT = CHUNK / 64;
  __shared__ ushort Ks[2][64 * 64];
  __shared__ ushort Vs[2][64 * 64];

  const int bh = blockIdx.x, b = bh >> 3;
  const int sp = blockIdx.z;
  const int jb = sp * CHUNK;
  const int t = threadIdx.x, lane = t & 63, w = t >> 6;
  const int l31 = lane & 31, hi = lane >> 5;
  const int q0 = blockIdx.y * 128 + w * 32;

  const ushort* Qh = Qb + (size_t)bh * 131072;
  const ushort* Kh = Kb + (size_t)bh * 131072;
  const ushort* Vh = VT + (size_t)bh * 131072;
  const int* mp = msk + b * 2048 + 4 * hi;

  const int srow = lane >> 3;
  const int soff = ((lane & 7) * 16) ^ ((srow & 7) << 4);

  auto stage = [&](int buf, int j0) {
    const char* kg = (const char*)Kh + ((size_t)(j0 + 16 * w + srow)) * 128 + soff;
    __builtin_amdgcn_global_load_lds((const GAS void*)kg,
        (LAS void*)&Ks[buf][16 * w * 64], 16, 0, 0);
    __builtin_amdgcn_global_load_lds((const GAS void*)(kg + 1024),
        (LAS void*)&Ks[buf][(16 * w + 8) * 64], 16, 0, 0);
    const char* vg = (const char*)Vh + ((size_t)(16 * w + srow)) * 4096 + (size_t)j0 * 2 + soff;
    __builtin_amdgcn_global_load_lds((const GAS void*)vg,
        (LAS void*)&Vs[buf][16 * w * 64], 16, 0, 0);
    __builtin_amdgcn_global_load_lds((const GAS void*)(vg + 8 * 4096),
        (LAS void*)&Vs[buf][(16 * w + 8) * 64], 16, 0, 0);
  };

  bf16x8 qf[4];
  #pragma unroll
  for (int kk = 0; kk < 4; kk++)
    qf[kk] = *(const bf16x8*)(Qh + (size_t)(q0 + l31) * 64 + kk * 16 + 8 * hi);

  f32x16 o0 = {}, o1 = {};
  float m = -1e30f, lsum = 0.f;
  const float sc = 0.18033688011112042f;  // (1/8) * log2(e)

  stage(0, jb);
  __syncthreads();

  for (int tt = 0; tt < NT; ++tt) {
    const int cur = tt & 1;
    if (tt + 1 < NT) stage(cur ^ 1, jb + (tt + 1) * 64);

    #pragma unroll
    for (int js = 0; js < 2; ++js) {
      const int jloc = js * 32;
      const int j0 = jb + tt * 64 + jloc;

      int32x4 mv0 = *(const int32x4*)(mp + j0);
      int32x4 mv1 = *(const int32x4*)(mp + j0 + 8);
      int32x4 mv2 = *(const int32x4*)(mp + j0 + 16);
      int32x4 mv3 = *(const int32x4*)(mp + j0 + 24);

      const int krow = jloc + l31;
      const unsigned rsw = (unsigned)((l31 & 7) << 4);
      const char* kbase = (const char*)&Ks[cur][0] + krow * 128;
      bf16x8 kf0 = *(const bf16x8*)(kbase + ((0  + hi * 16) ^ rsw));
      bf16x8 kf1 = *(const bf16x8*)(kbase + ((32 + hi * 16) ^ rsw));
      bf16x8 kf2 = *(const bf16x8*)(kbase + ((64 + hi * 16) ^ rsw));
      bf16x8 kf3 = *(const bf16x8*)(kbase + ((96 + hi * 16) ^ rsw));

      f32x16 z = {};
      f32x16 s = mfma32(kf0, qf[0], z);
      s = mfma32(kf1, qf[1], s);
      s = mfma32(kf2, qf[2], s);
      s = mfma32(kf3, qf[3], s);

      const char* vb0 = (const char*)&Vs[cur][0] + l31 * 128;
      const char* vb1 = vb0 + 32 * 128;
      const unsigned vc0 = (unsigned)((jloc * 2 + hi * 16) ^ rsw);
      const unsigned vc1 = (unsigned)((jloc * 2 + 32 + hi * 16) ^ rsw);
      bf16x8 vf00 = *(const bf16x8*)(vb0 + vc0);
      bf16x8 vf01 = *(const bf16x8*)(vb0 + vc1);
      bf16x8 vf10 = *(const bf16x8*)(vb1 + vc0);
      bf16x8 vf11 = *(const bf16x8*)(vb1 + vc1);

      float pv[16];
      #pragma unroll
      for (int e = 0; e < 4; e++) {
        pv[e]      = mv0[e] ? s[e]      * sc : -1e30f;
        pv[4 + e]  = mv1[e] ? s[4 + e]  * sc : -1e30f;
        pv[8 + e]  = mv2[e] ? s[8 + e]  * sc : -1e30f;
        pv[12 + e] = mv3[e] ? s[12 + e] * sc : -1e30f;
      }

      float t0 = fmaxf(fmaxf(pv[0],  pv[1]),  pv[2]);
      float t1 = fmaxf(fmaxf(pv[3],  pv[4]),  pv[5]);
      float t2 = fmaxf(fmaxf(pv[6],  pv[7]),  pv[8]);
      float t3 = fmaxf(fmaxf(pv[9],  pv[10]), pv[11]);
      float t4 = fmaxf(fmaxf(pv[12], pv[13]), pv[14]);
      float pm = fmaxf(fmaxf(fmaxf(t0, t1), t2), fmaxf(fmaxf(t3, t4), pv[15]));
      pm = fmaxf(pm, __shfl_xor(pm, 32));

      if (!__all(pm <= m + 8.f)) {
        float mn = fmaxf(m, pm);
        float al = exp2f(m - mn);
        lsum *= al;
        #pragma unroll
        for (int r = 0; r < 16; r++) { o0[r] *= al; o1[r] *= al; }
        m = mn;
      }

      #pragma unroll
      for (int r = 0; r < 16; r++) pv[r] = exp2f(pv[r] - m);
      float a0 = (pv[0] + pv[1]) + (pv[2] + pv[3]);
      float a1 = (pv[4] + pv[5]) + (pv[6] + pv[7]);
      float a2 = (pv[8] + pv[9]) + (pv[10] + pv[11]);
      float a3 = (pv[12] + pv[13]) + (pv[14] + pv[15]);
      float rs = (a0 + a1) + (a2 + a3);
      rs += __shfl_xor(rs, 32);
      lsum += rs;

      unsigned pk01 = cvtpk(pv[0],  pv[1]),  pk23 = cvtpk(pv[2],  pv[3]);
      unsigned pk45 = cvtpk(pv[4],  pv[5]),  pk67 = cvtpk(pv[6],  pv[7]);
      unsigned pk89 = cvtpk(pv[8],  pv[9]),  pkAB = cvtpk(pv[10], pv[11]);
      unsigned pkCD = cvtpk(pv[12], pv[13]), pkEF = cvtpk(pv[14], pv[15]);
      plswap(pk01, pk45);
      plswap(pk23, pk67);
      plswap(pk89, pkCD);
      plswap(pkAB, pkEF);
      union { unsigned u[4]; bf16x8 v; } pf0, pf1;
      pf0.u[0] = pk01; pf0.u[1] = pk23; pf0.u[2] = pk45; pf0.u[3] = pk67;
      pf1.u[0] = pk89; pf1.u[1] = pkAB; pf1.u[2] = pkCD; pf1.u[3] = pkEF;

      o0 = mfma32(vf00, pf0.v, o0);
      o0 = mfma32(vf01, pf1.v, o0);
      o1 = mfma32(vf10, pf0.v, o1);
      o1 = mfma32(vf11, pf1.v, o1);
    }
    __syncthreads();
  }

  float inv = lsum > 0.f ? 1.0f / lsum : 0.f;
  const int q = q0 + l31;
  ushort* op = Opart + (size_t)sp * 4194304 + ((size_t)(bh * 2048 + q)) * 64;
  #pragma unroll
  for (int grp = 0; grp < 4; grp++) {
    int d0 = grp * 8 + 4 * hi;
    uint32x2 w0, w1;
    w0[0] = cvtpk(o0[4 * grp] * inv, o0[4 * grp + 1] * inv);
    w0[1] = cvtpk(o0[4 * grp + 2] * inv, o0[4 * grp + 3] * inv);
    w1[0] = cvtpk(o1[4 * grp] * inv, o1[4 * grp + 1] * inv);
    w1[1] = cvtpk(o1[4 * grp + 2] * inv, o1[4 * grp + 3] * inv);
    *(uint32x2*)(op + d0)      = w0;
    *(uint32x2*)(op + 32 + d0) = w1;
  }
  if (hi == 0) {
    float2 v; v.x = m; v.y = lsum;
    Ml[sp * 65536 + bh * 2048 + q] = v;
  }
}

// Combine 4 split partials: AO[b,q,h*64+d] = sum_s w_s * Opart_s[bh,q,d]
__global__ __launch_bounds__(256)
void reduce_k(const ushort* __restrict__ Opart, const float2* __restrict__ Ml,
              ushort* __restrict__ AO)
{
  const int idx = blockIdx.x * 256 + threadIdx.x;   // 524288 total
  const int d8 = idx & 7, q = (idx >> 3) & 2047, bh = idx >> 14;
  const int b = bh >> 3, h = bh & 7;

  float2 ml[4];
  float M = -1e30f;
  #pragma unroll
  for (int s = 0; s < 4; s++) {
    ml[s] = Ml[s * 65536 + bh * 2048 + q];
    M = fmaxf(M, ml[s].x);
  }
  float wgt[4], L = 0.f;
  #pragma unroll
  for (int s = 0; s < 4; s++) {
    wgt[s] = ml[s].y * exp2f(ml[s].x - M);
    L += wgt[s];
  }
  float invL = 1.f / L;

  float acc[8] = {0.f,0.f,0.f,0.f,0.f,0.f,0.f,0.f};
  #pragma unroll
  for (int s = 0; s < 4; s++) {
    bf16x8 v = *(const bf16x8*)(Opart + (size_t)s * 4194304 +
                                ((size_t)(bh * 2048 + q)) * 64 + d8 * 8);
    float ws = wgt[s] * invL;
    #pragma unroll
    for (int e = 0; e < 8; e++) acc[e] += ws * bf2f(v[e]);
  }

  union { unsigned u[4]; int32x4 v; } pk;
  pk.u[0] = cvtpk(acc[0], acc[1]);
  pk.u[1] = cvtpk(acc[2], acc[3]);
  pk.u[2] = cvtpk(acc[4], acc[5]);
  pk.u[3] = cvtpk(acc[6], acc[7]);
  *(int32x4*)(AO + ((size_t)(b * 2048 + q)) * 512 + h * 64 + d8 * 8) = pk.v;
}

extern "C" void kernel_launch(void* const* d_in, const int* in_sizes, int n_in,
                              void* d_out, int out_size, void* d_ws, size_t ws_size,
                              hipStream_t stream)
{
  const float* x   = (const float*)d_in[0];
  const float* ctx = (const float*)d_in[1];
  const int*   mk  = (const int*)d_in[2];
  const float* Wq  = (const float*)d_in[3];
  const float* Wk  = (const float*)d_in[4];
  const float* Wv  = (const float*)d_in[5];
  const float* Wv_ = (const float*)d_in[5];
  const float* Wo  = (const float*)d_in[6];
  const float* bo  = (const float*)d_in[7];
  float* out = (float*)d_out;
  (void)Wv_;

  // Workspace plan (59 MB total; proven ws >= 66 MB):
  //  [0,8M):   Qb   [32][2048][64] bf16   -- later aliased as AO (reduce_k out)
  //  [8M,16M): Kb
  //  [16M,24M):VT   [32][64][2048]
  //  [24M,25M):WoT  [1024][512] bf16
  //  [25M,59M):R2 time-shared:
  //     prepass view: xb 16M | cb 12M | WqT 1M | WkT .75M | WvT .75M
  //     attn view:    Opart 32M | Ml 2M
  ushort* Qb  = (ushort*)d_ws;
  ushort* Kb  = Qb + 4194304;
  ushort* VT  = Kb + 4194304;
  ushort* WoT = VT + 4194304;
  ushort* R2  = WoT + 524288;
  ushort* xb  = R2;
  ushort* cb  = xb + 8388608;
  ushort* WqT = cb + 6291456;
  ushort* WkT = WqT + 524288;
  ushort* WvT = WkT + 393216;
  ushort* Opart = R2;
  float2* Ml    = (float2*)(R2 + 16777216);
  ushort* AO    = Qb;

  cvt_k<<<2048, 256, 0, stream>>>(x, ctx, xb, cb);
  wtcvt_k<<<448, 256, 0, stream>>>(Wq, Wk, Wv, Wo, WqT, WkT, WvT, WoT);
  mm_k<0><<<768, 256, 0, stream>>>(xb, cb, WqT, WkT, WvT, Qb, Kb, VT,
                                   nullptr, nullptr, nullptr, nullptr);
  attn_k<<<dim3(32, 16, 4), 256, 0, stream>>>(Qb, Kb, VT, mk, Opart, Ml);
  reduce_k<<<2048, 256, 0, stream>>>(Opart, Ml, AO);
  mm_k<1><<<512, 256, 0, stream>>>(nullptr, nullptr, nullptr, nullptr, nullptr,
                                   nullptr, nullptr, nullptr, AO, WoT, out, bo);
}

// Round 6
// 162.299 us; speedup vs baseline: 1.8480x; 1.0327x over previous
//
#include <hip/hip_runtime.h>
#include <hip/hip_bf16.h>

typedef __attribute__((ext_vector_type(4)))  float  f32x4;
typedef __attribute__((ext_vector_type(16))) float  f32x16;
typedef __attribute__((ext_vector_type(8)))  short  bf16x8;
typedef __attribute__((ext_vector_type(4)))  int    int32x4;
typedef __attribute__((ext_vector_type(2)))  unsigned int uint32x2;

#define DEVINL static __device__ __forceinline__
#define GAS __attribute__((address_space(1)))
#define LAS __attribute__((address_space(3)))

DEVINL ushort f2bf(float f) {
  unsigned u = __builtin_bit_cast(unsigned, f);
  unsigned r = u + 0x7fffu + ((u >> 16) & 1u);
  return (ushort)(r >> 16);
}

DEVINL unsigned cvtpk(float lo, float hi) {
  unsigned r;
  asm("v_cvt_pk_bf16_f32 %0, %1, %2" : "=v"(r) : "v"(lo), "v"(hi));
  return r;
}

DEVINL void plswap(unsigned &a, unsigned &b) {
  asm("v_permlane32_swap_b32 %0, %1" : "+v"(a), "+v"(b));
}

DEVINL float bf2f(short s) {
  return __builtin_bit_cast(float, ((unsigned)(ushort)s) << 16);
}

DEVINL f32x4 mfma16(bf16x8 a, bf16x8 b, f32x4 c) {
  return __builtin_amdgcn_mfma_f32_16x16x32_bf16(a, b, c, 0, 0, 0);
}
DEVINL f32x16 mfma32(bf16x8 a, bf16x8 b, f32x16 c) {
  return __builtin_amdgcn_mfma_f32_32x32x16_bf16(a, b, c, 0, 0, 0);
}

// ------------------------------------------------------------ pre-pass: f32 -> bf16 (+ mask -> float bias)
__global__ __launch_bounds__(256)
void cvt_k(const float* __restrict__ x, const float* __restrict__ ctx,
           ushort* __restrict__ xb, ushort* __restrict__ cb,
           const int* __restrict__ msk, float* __restrict__ mb)
{
  const int NX = 8388608, NC = 6291456;          // elems
  int tid = blockIdx.x * 256 + threadIdx.x;
  if (tid < 8192) mb[tid] = msk[tid] ? 0.f : -1e30f;
  for (int i = tid; i < (NX + NC) / 8; i += 2048 * 256) {
    int e = i * 8;
    const float* s; ushort* d;
    if (e < NX) { s = x + e; d = xb + e; }
    else        { s = ctx + (e - NX); d = cb + (e - NX); }
    f32x4 v0 = *(const f32x4*)s;
    f32x4 v1 = *(const f32x4*)(s + 4);
    union { unsigned u[4]; int32x4 v; } pk;
    pk.u[0] = cvtpk(v0[0], v0[1]);
    pk.u[1] = cvtpk(v0[2], v0[3]);
    pk.u[2] = cvtpk(v1[0], v1[1]);
    pk.u[3] = cvtpk(v1[2], v1[3]);
    *(int32x4*)d = pk.v;
  }
}

// ------------------------------------------------------------ pre-pass: W [K][N] f32 -> W^T [N][K] bf16
__global__ __launch_bounds__(256)
void wtcvt_k(const float* __restrict__ Wq, const float* __restrict__ Wk,
             const float* __restrict__ Wv, const float* __restrict__ Wo,
             ushort* __restrict__ WqT, ushort* __restrict__ WkT,
             ushort* __restrict__ WvT, ushort* __restrict__ WoT)
{
  __shared__ ushort Ts[64][72];
  int id = blockIdx.x;
  const float* src; ushort* dst; int Kd, Nd, lid;
  if (id < 128)      { src = Wq; dst = WqT; Kd = 1024; Nd = 512;  lid = id; }
  else if (id < 224) { src = Wk; dst = WkT; Kd = 768;  Nd = 512;  lid = id - 128; }
  else if (id < 320) { src = Wv; dst = WvT; Kd = 768;  Nd = 512;  lid = id - 224; }
  else               { src = Wo; dst = WoT; Kd = 512;  Nd = 1024; lid = id - 320; }
  const int sh = (Nd == 512) ? 3 : 4;            // Nd/64 = 8 or 16
  const int kb = lid >> sh, nb = lid & ((1 << sh) - 1);
  const int k0 = kb * 64, n0 = nb * 64;
  const int t = threadIdx.x;
  const int r = t >> 2, c0 = (t & 3) * 16;

  const float* sp = src + (size_t)(k0 + r) * Nd + n0 + c0;
  f32x4 v0 = *(const f32x4*)(sp);
  f32x4 v1 = *(const f32x4*)(sp + 4);
  f32x4 v2 = *(const f32x4*)(sp + 8);
  f32x4 v3 = *(const f32x4*)(sp + 12);
  #pragma unroll
  for (int e = 0; e < 4; e++) {
    Ts[c0 + e][r]      = f2bf(v0[e]);
    Ts[c0 + 4 + e][r]  = f2bf(v1[e]);
    Ts[c0 + 8 + e][r]  = f2bf(v2[e]);
    Ts[c0 + 12 + e][r] = f2bf(v3[e]);
  }
  __syncthreads();
  const int n = t >> 2, kc = (t & 3) * 16;
  bf16x8 o0 = *(const bf16x8*)&Ts[n][kc];
  bf16x8 o1 = *(const bf16x8*)&Ts[n][kc + 8];
  ushort* dp = dst + (size_t)(n0 + n) * Kd + k0 + kc;
  *(bf16x8*)dp       = o0;
  *(bf16x8*)(dp + 8) = o1;
}

// ------------------------------------------------------------ GEMM (m97 structure)
// A [M,K] bf16, BT [N,K] bf16.  128x128 tile, BK=32, 4 waves, dbuf LDS via
// global_load_lds w=16.  XOR swizzle on source + read (rule 21).
// PHASE 0: fused QKV, 768 blocks.  PHASE 1: out-proj, 512 blocks.
template<int PHASE>
__global__ __launch_bounds__(256)
void mm_k(const ushort* __restrict__ xb, const ushort* __restrict__ cb,
          const ushort* __restrict__ WqT, const ushort* __restrict__ WkT,
          const ushort* __restrict__ WvT,
          ushort* __restrict__ Qb, ushort* __restrict__ Kb, ushort* __restrict__ VT,
          const ushort* __restrict__ AO, const ushort* __restrict__ WoT,
          float* __restrict__ out, const float* __restrict__ bias)
{
  __shared__ ushort As[2][128 * 32];
  __shared__ ushort Bs[2][128 * 32];

  const ushort* A; const ushort* BT; ushort* Cw = nullptr;
  int Kd, mode, m0, n0;
  if (PHASE == 0) {
    int id = blockIdx.x;
    id = (id & 7) * 96 + (id >> 3);              // XCD swizzle (768 % 8 == 0)
    const int which = id >> 8, local = id & 255;
    m0 = (local >> 2) * 128; n0 = (local & 3) * 128;
    if (which == 0)      { A = xb; BT = WqT; Cw = Qb; Kd = 1024; mode = 1; }
    else if (which == 1) { A = cb; BT = WkT; Cw = Kb; Kd = 768;  mode = 1; }
    else                 { A = cb; BT = WvT; Cw = VT; Kd = 768;  mode = 2; }
  } else {
    int id = blockIdx.x;
    id = (id & 7) * 64 + (id >> 3);              // 512 % 8 == 0
    m0 = (id >> 3) * 128; n0 = (id & 7) * 128;
    A = AO; BT = WoT; Kd = 512; mode = 0;
  }

  const int t = threadIdx.x, lane = t & 63, w = t >> 6;
  const int wr = w >> 1, wc = w & 1;
  const int g = lane >> 4, ql = lane & 15;

  const int srowo = 16 * w + (lane >> 2);
  const int sgg = (lane & 3) ^ ((lane >> 3) & 3);

  f32x4 acc[4][4];
  #pragma unroll
  for (int i = 0; i < 4; i++)
    #pragma unroll
    for (int j = 0; j < 4; j++) acc[i][j] = (f32x4){0.f, 0.f, 0.f, 0.f};

  auto stage = [&](int buf, int k0) {
    #pragma unroll
    for (int i = 0; i < 2; i++) {
      const int row = i * 64 + srowo;
      const ushort* asrc = A + (size_t)(m0 + row) * Kd + k0 + sgg * 8;
      __builtin_amdgcn_global_load_lds((const GAS void*)asrc,
          (LAS void*)&As[buf][(i * 64 + 16 * w) * 32], 16, 0, 0);
      const ushort* bsrc = BT + (size_t)(n0 + row) * Kd + k0 + sgg * 8;
      __builtin_amdgcn_global_load_lds((const GAS void*)bsrc,
          (LAS void*)&Bs[buf][(i * 64 + 16 * w) * 32], 16, 0, 0);
    }
  };

  const int NK = Kd >> 5;
  stage(0, 0);
  __syncthreads();

  const int sel = (ql >> 1) & 3;
  const int koff = (g ^ sel) * 8;

  for (int tt = 0; tt < NK; tt++) {
    const int cur = tt & 1;
    if (tt + 1 < NK) stage(cur ^ 1, (tt + 1) * 32);

    bf16x8 af[4], bfr[4];
    #pragma unroll
    for (int i = 0; i < 4; i++) {
      af[i]  = *(const bf16x8*)&As[cur][(wr * 64 + i * 16 + ql) * 32 + koff];
      bfr[i] = *(const bf16x8*)&Bs[cur][(wc * 64 + i * 16 + ql) * 32 + koff];
    }
    #pragma unroll
    for (int i = 0; i < 4; i++)
      #pragma unroll
      for (int j = 0; j < 4; j++)
        acc[i][j] = mfma16(af[i], bfr[j], acc[i][j]);
    __syncthreads();
  }

  #pragma unroll
  for (int i = 0; i < 4; i++) {
    #pragma unroll
    for (int j = 0; j < 4; j++) {
      int col = n0 + wc * 64 + j * 16 + ql;
      #pragma unroll
      for (int r = 0; r < 4; r++) {
        int mrow = m0 + wr * 64 + i * 16 + g * 4 + r;
        float v = acc[i][j][r];
        if (PHASE == 1) {
          out[(size_t)mrow * 1024 + col] = v + bias[col];
        } else {
          int b = mrow >> 11, nn = mrow & 2047;
          int hh = col >> 6, dd = col & 63;
          size_t base = (size_t)(b * 8 + hh) * 131072;
          if (mode == 1) Cw[base + (size_t)nn * 64 + dd]   = f2bf(v);
          else           Cw[base + (size_t)dd * 2048 + nn] = f2bf(v);
        }
      }
    }
  }
}

// ------------------------------------------------------------ attention
// Fully-transposed 32x32 flash attention, KV-split=4, LDS-staged dbuf K/V via
// global_load_lds, XOR swizzle on source + read.  Mask pre-baked as additive
// f32 bias mb[b][j] (0 or -1e30): pv = fma(s, sc, mb) — 1 VALU op/elem.
__global__ __launch_bounds__(256)
void attn_k(const ushort* __restrict__ Qb, const ushort* __restrict__ Kb,
            const ushort* __restrict__ VT, const float* __restrict__ mb,
            ushort* __restrict__ Opart, float2* __restrict__ Ml)
{
  constexpr int CHUNK = 512, NT = CHUNK / 64;
  __shared__ ushort Ks[2][64 * 64];
  __shared__ ushort Vs[2][64 * 64];

  const int bh = blockIdx.x, b = bh >> 3;
  const int sp = blockIdx.z;
  const int jb = sp * CHUNK;
  const int t = threadIdx.x, lane = t & 63, w = t >> 6;
  const int l31 = lane & 31, hi = lane >> 5;
  const int q0 = blockIdx.y * 128 + w * 32;

  const ushort* Qh = Qb + (size_t)bh * 131072;
  const ushort* Kh = Kb + (size_t)bh * 131072;
  const ushort* Vh = VT + (size_t)bh * 131072;
  const float* mp = mb + b * 2048 + 4 * hi;

  const int srow = lane >> 3;
  const int soff = ((lane & 7) * 16) ^ ((srow & 7) << 4);

  auto stage = [&](int buf, int j0) {
    const char* kg = (const char*)Kh + ((size_t)(j0 + 16 * w + srow)) * 128 + soff;
    __builtin_amdgcn_global_load_lds((const GAS void*)kg,
        (LAS void*)&Ks[buf][16 * w * 64], 16, 0, 0);
    __builtin_amdgcn_global_load_lds((const GAS void*)(kg + 1024),
        (LAS void*)&Ks[buf][(16 * w + 8) * 64], 16, 0, 0);
    const char* vg = (const char*)Vh + ((size_t)(16 * w + srow)) * 4096 + (size_t)j0 * 2 + soff;
    __builtin_amdgcn_global_load_lds((const GAS void*)vg,
        (LAS void*)&Vs[buf][16 * w * 64], 16, 0, 0);
    __builtin_amdgcn_global_load_lds((const GAS void*)(vg + 8 * 4096),
        (LAS void*)&Vs[buf][(16 * w + 8) * 64], 16, 0, 0);
  };

  bf16x8 qf[4];
  #pragma unroll
  for (int kk = 0; kk < 4; kk++)
    qf[kk] = *(const bf16x8*)(Qh + (size_t)(q0 + l31) * 64 + kk * 16 + 8 * hi);

  f32x16 o0 = {}, o1 = {};
  float m = -1e30f, lsum = 0.f;
  const float sc = 0.18033688011112042f;  // (1/8) * log2(e)

  stage(0, jb);
  __syncthreads();

  for (int tt = 0; tt < NT; ++tt) {
    const int cur = tt & 1;
    if (tt + 1 < NT) stage(cur ^ 1, jb + (tt + 1) * 64);

    #pragma unroll
    for (int js = 0; js < 2; ++js) {
      const int jloc = js * 32;
      const int j0 = jb + tt * 64 + jloc;

      f32x4 mb0 = *(const f32x4*)(mp + j0);
      f32x4 mb1 = *(const f32x4*)(mp + j0 + 8);
      f32x4 mb2 = *(const f32x4*)(mp + j0 + 16);
      f32x4 mb3 = *(const f32x4*)(mp + j0 + 24);

      const int krow = jloc + l31;
      const unsigned rsw = (unsigned)((l31 & 7) << 4);
      const char* kbase = (const char*)&Ks[cur][0] + krow * 128;
      bf16x8 kf0 = *(const bf16x8*)(kbase + ((0  + hi * 16) ^ rsw));
      bf16x8 kf1 = *(const bf16x8*)(kbase + ((32 + hi * 16) ^ rsw));
      bf16x8 kf2 = *(const bf16x8*)(kbase + ((64 + hi * 16) ^ rsw));
      bf16x8 kf3 = *(const bf16x8*)(kbase + ((96 + hi * 16) ^ rsw));

      __builtin_amdgcn_s_setprio(1);
      f32x16 z = {};
      f32x16 s = mfma32(kf0, qf[0], z);
      s = mfma32(kf1, qf[1], s);
      s = mfma32(kf2, qf[2], s);
      s = mfma32(kf3, qf[3], s);
      __builtin_amdgcn_s_setprio(0);

      const char* vb0 = (const char*)&Vs[cur][0] + l31 * 128;
      const char* vb1 = vb0 + 32 * 128;
      const unsigned vc0 = (unsigned)((jloc * 2 + hi * 16) ^ rsw);
      const unsigned vc1 = (unsigned)((jloc * 2 + 32 + hi * 16) ^ rsw);
      bf16x8 vf00 = *(const bf16x8*)(vb0 + vc0);
      bf16x8 vf01 = *(const bf16x8*)(vb0 + vc1);
      bf16x8 vf10 = *(const bf16x8*)(vb1 + vc0);
      bf16x8 vf11 = *(const bf16x8*)(vb1 + vc1);

      // pv = s * sc + mb  (single v_fma per element; -1e30 absorbs the product)
      float pv[16];
      #pragma unroll
      for (int e = 0; e < 4; e++) {
        pv[e]      = fmaf(s[e],      sc, mb0[e]);
        pv[4 + e]  = fmaf(s[4 + e],  sc, mb1[e]);
        pv[8 + e]  = fmaf(s[8 + e],  sc, mb2[e]);
        pv[12 + e] = fmaf(s[12 + e], sc, mb3[e]);
      }

      float t0 = fmaxf(fmaxf(pv[0],  pv[1]),  pv[2]);
      float t1 = fmaxf(fmaxf(pv[3],  pv[4]),  pv[5]);
      float t2 = fmaxf(fmaxf(pv[6],  pv[7]),  pv[8]);
      float t3 = fmaxf(fmaxf(pv[9],  pv[10]), pv[11]);
      float t4 = fmaxf(fmaxf(pv[12], pv[13]), pv[14]);
      float pm = fmaxf(fmaxf(fmaxf(t0, t1), t2), fmaxf(fmaxf(t3, t4), pv[15]));
      pm = fmaxf(pm, __shfl_xor(pm, 32));

      if (!__all(pm <= m + 8.f)) {
        float mn = fmaxf(m, pm);
        float al = exp2f(m - mn);
        lsum *= al;
        #pragma unroll
        for (int r = 0; r < 16; r++) { o0[r] *= al; o1[r] *= al; }
        m = mn;
      }

      #pragma unroll
      for (int r = 0; r < 16; r++) pv[r] = exp2f(pv[r] - m);
      float a0 = (pv[0] + pv[1]) + (pv[2] + pv[3]);
      float a1 = (pv[4] + pv[5]) + (pv[6] + pv[7]);
      float a2 = (pv[8] + pv[9]) + (pv[10] + pv[11]);
      float a3 = (pv[12] + pv[13]) + (pv[14] + pv[15]);
      float rs = (a0 + a1) + (a2 + a3);
      rs += __shfl_xor(rs, 32);
      lsum += rs;

      unsigned pk01 = cvtpk(pv[0],  pv[1]),  pk23 = cvtpk(pv[2],  pv[3]);
      unsigned pk45 = cvtpk(pv[4],  pv[5]),  pk67 = cvtpk(pv[6],  pv[7]);
      unsigned pk89 = cvtpk(pv[8],  pv[9]),  pkAB = cvtpk(pv[10], pv[11]);
      unsigned pkCD = cvtpk(pv[12], pv[13]), pkEF = cvtpk(pv[14], pv[15]);
      plswap(pk01, pk45);
      plswap(pk23, pk67);
      plswap(pk89, pkCD);
      plswap(pkAB, pkEF);
      union { unsigned u[4]; bf16x8 v; } pf0, pf1;
      pf0.u[0] = pk01; pf0.u[1] = pk23; pf0.u[2] = pk45; pf0.u[3] = pk67;
      pf1.u[0] = pk89; pf1.u[1] = pkAB; pf1.u[2] = pkCD; pf1.u[3] = pkEF;

      __builtin_amdgcn_s_setprio(1);
      o0 = mfma32(vf00, pf0.v, o0);
      o0 = mfma32(vf01, pf1.v, o0);
      o1 = mfma32(vf10, pf0.v, o1);
      o1 = mfma32(vf11, pf1.v, o1);
      __builtin_amdgcn_s_setprio(0);
    }
    __syncthreads();
  }

  float inv = lsum > 0.f ? 1.0f / lsum : 0.f;
  const int q = q0 + l31;
  ushort* op = Opart + (size_t)sp * 4194304 + ((size_t)(bh * 2048 + q)) * 64;
  #pragma unroll
  for (int grp = 0; grp < 4; grp++) {
    int d0 = grp * 8 + 4 * hi;
    uint32x2 w0, w1;
    w0[0] = cvtpk(o0[4 * grp] * inv, o0[4 * grp + 1] * inv);
    w0[1] = cvtpk(o0[4 * grp + 2] * inv, o0[4 * grp + 3] * inv);
    w1[0] = cvtpk(o1[4 * grp] * inv, o1[4 * grp + 1] * inv);
    w1[1] = cvtpk(o1[4 * grp + 2] * inv, o1[4 * grp + 3] * inv);
    *(uint32x2*)(op + d0)      = w0;
    *(uint32x2*)(op + 32 + d0) = w1;
  }
  if (hi == 0) {
    float2 v; v.x = m; v.y = lsum;
    Ml[sp * 65536 + bh * 2048 + q] = v;
  }
}

// Combine 4 split partials: AO[b,q,h*64+d] = sum_s w_s * Opart_s[bh,q,d]
__global__ __launch_bounds__(256)
void reduce_k(const ushort* __restrict__ Opart, const float2* __restrict__ Ml,
              ushort* __restrict__ AO)
{
  const int idx = blockIdx.x * 256 + threadIdx.x;   // 524288 total
  const int d8 = idx & 7, q = (idx >> 3) & 2047, bh = idx >> 14;
  const int b = bh >> 3, h = bh & 7;

  float2 ml[4];
  float M = -1e30f;
  #pragma unroll
  for (int s = 0; s < 4; s++) {
    ml[s] = Ml[s * 65536 + bh * 2048 + q];
    M = fmaxf(M, ml[s].x);
  }
  float wgt[4], L = 0.f;
  #pragma unroll
  for (int s = 0; s < 4; s++) {
    wgt[s] = ml[s].y * exp2f(ml[s].x - M);
    L += wgt[s];
  }
  float invL = 1.f / L;

  float acc[8] = {0.f,0.f,0.f,0.f,0.f,0.f,0.f,0.f};
  #pragma unroll
  for (int s = 0; s < 4; s++) {
    bf16x8 v = *(const bf16x8*)(Opart + (size_t)s * 4194304 +
                                ((size_t)(bh * 2048 + q)) * 64 + d8 * 8);
    float ws = wgt[s] * invL;
    #pragma unroll
    for (int e = 0; e < 8; e++) acc[e] += ws * bf2f(v[e]);
  }

  union { unsigned u[4]; int32x4 v; } pk;
  pk.u[0] = cvtpk(acc[0], acc[1]);
  pk.u[1] = cvtpk(acc[2], acc[3]);
  pk.u[2] = cvtpk(acc[4], acc[5]);
  pk.u[3] = cvtpk(acc[6], acc[7]);
  *(int32x4*)(AO + ((size_t)(b * 2048 + q)) * 512 + h * 64 + d8 * 8) = pk.v;
}

extern "C" void kernel_launch(void* const* d_in, const int* in_sizes, int n_in,
                              void* d_out, int out_size, void* d_ws, size_t ws_size,
                              hipStream_t stream)
{
  const float* x   = (const float*)d_in[0];
  const float* ctx = (const float*)d_in[1];
  const int*   mk  = (const int*)d_in[2];
  const float* Wq  = (const float*)d_in[3];
  const float* Wk  = (const float*)d_in[4];
  const float* Wv  = (const float*)d_in[5];
  const float* Wo  = (const float*)d_in[6];
  const float* bo  = (const float*)d_in[7];
  float* out = (float*)d_out;

  // Workspace plan (~59 MB; ws >= 66 MB proven in earlier rounds):
  //  [0,8M):   Qb  -- later aliased as AO (reduce_k output)
  //  [8M,16M): Kb
  //  [16M,24M):VT
  //  [24M,25M):WoT [1024][512] bf16
  //  [25M,25M+32K): mb  float[4][2048]
  //  then R2 time-shared:
  //     prepass view: xb 16M | cb 12M | WqT 1M | WkT .75M | WvT .75M
  //     attn view:    Opart 32M | Ml 2M
  ushort* Qb  = (ushort*)d_ws;
  ushort* Kb  = Qb + 4194304;
  ushort* VT  = Kb + 4194304;
  ushort* WoT = VT + 4194304;
  float*  mb  = (float*)(WoT + 524288);
  ushort* R2  = WoT + 524288 + 16384;     // after mb (8192 floats)
  ushort* xb  = R2;
  ushort* cb  = xb + 8388608;
  ushort* WqT = cb + 6291456;
  ushort* WkT = WqT + 524288;
  ushort* WvT = WkT + 393216;
  ushort* Opart = R2;
  float2* Ml    = (float2*)(R2 + 16777216);
  ushort* AO    = Qb;

  cvt_k<<<2048, 256, 0, stream>>>(x, ctx, xb, cb, mk, mb);
  wtcvt_k<<<448, 256, 0, stream>>>(Wq, Wk, Wv, Wo, WqT, WkT, WvT, WoT);
  mm_k<0><<<768, 256, 0, stream>>>(xb, cb, WqT, WkT, WvT, Qb, Kb, VT,
                                   nullptr, nullptr, nullptr, nullptr);
  attn_k<<<dim3(32, 16, 4), 256, 0, stream>>>(Qb, Kb, VT, mb, Opart, Ml);
  reduce_k<<<2048, 256, 0, stream>>>(Opart, Ml, AO);
  mm_k<1><<<512, 256, 0, stream>>>(nullptr, nullptr, nullptr, nullptr, nullptr,
                                   nullptr, nullptr, nullptr, AO, WoT, out, bo);
}

// Round 9
// 159.438 us; speedup vs baseline: 1.8812x; 1.0179x over previous
//
#include <hip/hip_runtime.h>
#include <hip/hip_bf16.h>

typedef __attribute__((ext_vector_type(4)))  float  f32x4;
typedef __attribute__((ext_vector_type(16))) float  f32x16;
typedef __attribute__((ext_vector_type(8)))  short  bf16x8;
typedef __attribute__((ext_vector_type(4)))  int    int32x4;
typedef __attribute__((ext_vector_type(2)))  unsigned int uint32x2;

#define DEVINL static __device__ __forceinline__
#define GAS __attribute__((address_space(1)))
#define LAS __attribute__((address_space(3)))

DEVINL ushort f2bf(float f) {
  unsigned u = __builtin_bit_cast(unsigned, f);
  unsigned r = u + 0x7fffu + ((u >> 16) & 1u);
  return (ushort)(r >> 16);
}

DEVINL unsigned cvtpk(float lo, float hi) {
  unsigned r;
  asm("v_cvt_pk_bf16_f32 %0, %1, %2" : "=v"(r) : "v"(lo), "v"(hi));
  return r;
}

// ONLY safe with genuinely-distinct values in a and b (equal-valued operands
// may be register-coalesced into a self-swap no-op — rounds 7/8 lesson).
DEVINL void plswap(unsigned &a, unsigned &b) {
  asm("v_permlane32_swap_b32 %0, %1" : "+v"(a), "+v"(b));
}

DEVINL float bf2f(short s) {
  return __builtin_bit_cast(float, ((unsigned)(ushort)s) << 16);
}

DEVINL f32x4 mfma16(bf16x8 a, bf16x8 b, f32x4 c) {
  return __builtin_amdgcn_mfma_f32_16x16x32_bf16(a, b, c, 0, 0, 0);
}
DEVINL f32x16 mfma32(bf16x8 a, bf16x8 b, f32x16 c) {
  return __builtin_amdgcn_mfma_f32_32x32x16_bf16(a, b, c, 0, 0, 0);
}

// ------------------------------------------------------------ pre-pass: f32 -> bf16 (+ mask -> float bias)
__global__ __launch_bounds__(256)
void cvt_k(const float* __restrict__ x, const float* __restrict__ ctx,
           ushort* __restrict__ xb, ushort* __restrict__ cb,
           const int* __restrict__ msk, float* __restrict__ mb)
{
  const int NX = 8388608, NC = 6291456;          // elems
  int tid = blockIdx.x * 256 + threadIdx.x;
  if (tid < 8192) mb[tid] = msk[tid] ? 0.f : -1e30f;
  for (int i = tid; i < (NX + NC) / 8; i += 2048 * 256) {
    int e = i * 8;
    const float* s; ushort* d;
    if (e < NX) { s = x + e; d = xb + e; }
    else        { s = ctx + (e - NX); d = cb + (e - NX); }
    f32x4 v0 = *(const f32x4*)s;
    f32x4 v1 = *(const f32x4*)(s + 4);
    union { unsigned u[4]; int32x4 v; } pk;
    pk.u[0] = cvtpk(v0[0], v0[1]);
    pk.u[1] = cvtpk(v0[2], v0[3]);
    pk.u[2] = cvtpk(v1[0], v1[1]);
    pk.u[3] = cvtpk(v1[2], v1[3]);
    *(int32x4*)d = pk.v;
  }
}

// ------------------------------------------------------------ pre-pass: W [K][N] f32 -> W^T [N][K] bf16
__global__ __launch_bounds__(256)
void wtcvt_k(const float* __restrict__ Wq, const float* __restrict__ Wk,
             const float* __restrict__ Wv, const float* __restrict__ Wo,
             ushort* __restrict__ WqT, ushort* __restrict__ WkT,
             ushort* __restrict__ WvT, ushort* __restrict__ WoT)
{
  __shared__ ushort Ts[64][72];
  int id = blockIdx.x;
  const float* src; ushort* dst; int Kd, Nd, lid;
  if (id < 128)      { src = Wq; dst = WqT; Kd = 1024; Nd = 512;  lid = id; }
  else if (id < 224) { src = Wk; dst = WkT; Kd = 768;  Nd = 512;  lid = id - 128; }
  else if (id < 320) { src = Wv; dst = WvT; Kd = 768;  Nd = 512;  lid = id - 224; }
  else               { src = Wo; dst = WoT; Kd = 512;  Nd = 1024; lid = id - 320; }
  const int sh = (Nd == 512) ? 3 : 4;            // Nd/64 = 8 or 16
  const int kb = lid >> sh, nb = lid & ((1 << sh) - 1);
  const int k0 = kb * 64, n0 = nb * 64;
  const int t = threadIdx.x;
  const int r = t >> 2, c0 = (t & 3) * 16;

  const float* sp = src + (size_t)(k0 + r) * Nd + n0 + c0;
  f32x4 v0 = *(const f32x4*)(sp);
  f32x4 v1 = *(const f32x4*)(sp + 4);
  f32x4 v2 = *(const f32x4*)(sp + 8);
  f32x4 v3 = *(const f32x4*)(sp + 12);
  #pragma unroll
  for (int e = 0; e < 4; e++) {
    Ts[c0 + e][r]      = f2bf(v0[e]);
    Ts[c0 + 4 + e][r]  = f2bf(v1[e]);
    Ts[c0 + 8 + e][r]  = f2bf(v2[e]);
    Ts[c0 + 12 + e][r] = f2bf(v3[e]);
  }
  __syncthreads();
  const int n = t >> 2, kc = (t & 3) * 16;
  bf16x8 o0 = *(const bf16x8*)&Ts[n][kc];
  bf16x8 o1 = *(const bf16x8*)&Ts[n][kc + 8];
  ushort* dp = dst + (size_t)(n0 + n) * Kd + k0 + kc;
  *(bf16x8*)dp       = o0;
  *(bf16x8*)(dp + 8) = o1;
}

// ------------------------------------------------------------ GEMM (m97 structure)
// A [M,K] bf16, BT [N,K] bf16.  128x128 tile, BK=32, 4 waves, dbuf LDS via
// global_load_lds w=16.  XOR swizzle on source + read (rule 21).
// PHASE 0: fused QKV, 768 blocks.  PHASE 1: out-proj, 512 blocks.
template<int PHASE>
__global__ __launch_bounds__(256)
void mm_k(const ushort* __restrict__ xb, const ushort* __restrict__ cb,
          const ushort* __restrict__ WqT, const ushort* __restrict__ WkT,
          const ushort* __restrict__ WvT,
          ushort* __restrict__ Qb, ushort* __restrict__ Kb, ushort* __restrict__ VT,
          const ushort* __restrict__ AO, const ushort* __restrict__ WoT,
          float* __restrict__ out, const float* __restrict__ bias)
{
  __shared__ ushort As[2][128 * 32];
  __shared__ ushort Bs[2][128 * 32];

  const ushort* A; const ushort* BT; ushort* Cw = nullptr;
  int Kd, mode, m0, n0;
  if (PHASE == 0) {
    int id = blockIdx.x;
    id = (id & 7) * 96 + (id >> 3);              // XCD swizzle (768 % 8 == 0)
    const int which = id >> 8, local = id & 255;
    m0 = (local >> 2) * 128; n0 = (local & 3) * 128;
    if (which == 0)      { A = xb; BT = WqT; Cw = Qb; Kd = 1024; mode = 1; }
    else if (which == 1) { A = cb; BT = WkT; Cw = Kb; Kd = 768;  mode = 1; }
    else                 { A = cb; BT = WvT; Cw = VT; Kd = 768;  mode = 2; }
  } else {
    int id = blockIdx.x;
    id = (id & 7) * 64 + (id >> 3);              // 512 % 8 == 0
    m0 = (id >> 3) * 128; n0 = (id & 7) * 128;
    A = AO; BT = WoT; Kd = 512; mode = 0;
  }

  const int t = threadIdx.x, lane = t & 63, w = t >> 6;
  const int wr = w >> 1, wc = w & 1;
  const int g = lane >> 4, ql = lane & 15;

  const int srowo = 16 * w + (lane >> 2);
  const int sgg = (lane & 3) ^ ((lane >> 3) & 3);

  f32x4 acc[4][4];
  #pragma unroll
  for (int i = 0; i < 4; i++)
    #pragma unroll
    for (int j = 0; j < 4; j++) acc[i][j] = (f32x4){0.f, 0.f, 0.f, 0.f};

  auto stage = [&](int buf, int k0) {
    #pragma unroll
    for (int i = 0; i < 2; i++) {
      const int row = i * 64 + srowo;
      const ushort* asrc = A + (size_t)(m0 + row) * Kd + k0 + sgg * 8;
      __builtin_amdgcn_global_load_lds((const GAS void*)asrc,
          (LAS void*)&As[buf][(i * 64 + 16 * w) * 32], 16, 0, 0);
      const ushort* bsrc = BT + (size_t)(n0 + row) * Kd + k0 + sgg * 8;
      __builtin_amdgcn_global_load_lds((const GAS void*)bsrc,
          (LAS void*)&Bs[buf][(i * 64 + 16 * w) * 32], 16, 0, 0);
    }
  };

  const int NK = Kd >> 5;
  stage(0, 0);
  __syncthreads();

  const int sel = (ql >> 1) & 3;
  const int koff = (g ^ sel) * 8;

  for (int tt = 0; tt < NK; tt++) {
    const int cur = tt & 1;
    if (tt + 1 < NK) stage(cur ^ 1, (tt + 1) * 32);

    bf16x8 af[4], bfr[4];
    #pragma unroll
    for (int i = 0; i < 4; i++) {
      af[i]  = *(const bf16x8*)&As[cur][(wr * 64 + i * 16 + ql) * 32 + koff];
      bfr[i] = *(const bf16x8*)&Bs[cur][(wc * 64 + i * 16 + ql) * 32 + koff];
    }
    #pragma unroll
    for (int i = 0; i < 4; i++)
      #pragma unroll
      for (int j = 0; j < 4; j++)
        acc[i][j] = mfma16(af[i], bfr[j], acc[i][j]);
    __syncthreads();
  }

  #pragma unroll
  for (int i = 0; i < 4; i++) {
    #pragma unroll
    for (int j = 0; j < 4; j++) {
      int col = n0 + wc * 64 + j * 16 + ql;
      #pragma unroll
      for (int r = 0; r < 4; r++) {
        int mrow = m0 + wr * 64 + i * 16 + g * 4 + r;
        float v = acc[i][j][r];
        if (PHASE == 1) {
          out[(size_t)mrow * 1024 + col] = v + bias[col];
        } else {
          int b = mrow >> 11, nn = mrow & 2047;
          int hh = col >> 6, dd = col & 63;
          size_t base = (size_t)(b * 8 + hh) * 131072;
          if (mode == 1) Cw[base + (size_t)nn * 64 + dd]   = f2bf(v);
          else           Cw[base + (size_t)dd * 2048 + nn] = f2bf(v);
        }
      }
    }
  }
}

// ------------------------------------------------------------ attention
// Fully-transposed 32x32 flash attention, KV-split=4, 8 waves/block (512 thr,
// q-tile 256), LDS-staged dbuf K/V via global_load_lds (1 gload each per wave
// per tile), XOR swizzle on source + read.  Mask as additive f32 bias.
// Cross-half reductions via __shfl_xor(…,32) (proven in rounds 2-6; the
// permlane-based replacement failed twice — equal-operand self-swap hazard).
__global__ __launch_bounds__(512)
void attn_k(const ushort* __restrict__ Qb, const ushort* __restrict__ Kb,
            const ushort* __restrict__ VT, const float* __restrict__ mb,
            ushort* __restrict__ Opart, float2* __restrict__ Ml)
{
  constexpr int CHUNK = 512, NT = CHUNK / 64;
  __shared__ ushort Ks[2][64 * 64];
  __shared__ ushort Vs[2][64 * 64];

  const int bh = blockIdx.x, b = bh >> 3;
  const int sp = blockIdx.z;
  const int jb = sp * CHUNK;
  const int t = threadIdx.x, lane = t & 63, w = t >> 6;   // w = 0..7
  const int l31 = lane & 31, hi = lane >> 5;
  const int q0 = blockIdx.y * 256 + w * 32;

  const ushort* Qh = Qb + (size_t)bh * 131072;
  const ushort* Kh = Kb + (size_t)bh * 131072;
  const ushort* Vh = VT + (size_t)bh * 131072;
  const float* mp = mb + b * 2048 + 4 * hi;

  // staging: each of the 8 waves stages 8 K-rows and 8 V-rows (1 gload each)
  const int srow = lane >> 3;                    // 0..7
  const int soff = ((lane & 7) * 16) ^ ((srow & 7) << 4);

  auto stage = [&](int buf, int j0) {
    const char* kg = (const char*)Kh + ((size_t)(j0 + 8 * w + srow)) * 128 + soff;
    __builtin_amdgcn_global_load_lds((const GAS void*)kg,
        (LAS void*)&Ks[buf][8 * w * 64], 16, 0, 0);
    const char* vg = (const char*)Vh + ((size_t)(8 * w + srow)) * 4096 + (size_t)j0 * 2 + soff;
    __builtin_amdgcn_global_load_lds((const GAS void*)vg,
        (LAS void*)&Vs[buf][8 * w * 64], 16, 0, 0);
  };

  bf16x8 qf[4];
  #pragma unroll
  for (int kk = 0; kk < 4; kk++)
    qf[kk] = *(const bf16x8*)(Qh + (size_t)(q0 + l31) * 64 + kk * 16 + 8 * hi);

  f32x16 o0 = {}, o1 = {};
  float m = -1e30f, lsum = 0.f;
  const float sc = 0.18033688011112042f;  // (1/8) * log2(e)

  stage(0, jb);
  __syncthreads();

  for (int tt = 0; tt < NT; ++tt) {
    const int cur = tt & 1;
    if (tt + 1 < NT) stage(cur ^ 1, jb + (tt + 1) * 64);

    #pragma unroll
    for (int js = 0; js < 2; ++js) {
      const int jloc = js * 32;
      const int j0 = jb + tt * 64 + jloc;

      f32x4 mb0 = *(const f32x4*)(mp + j0);
      f32x4 mb1 = *(const f32x4*)(mp + j0 + 8);
      f32x4 mb2 = *(const f32x4*)(mp + j0 + 16);
      f32x4 mb3 = *(const f32x4*)(mp + j0 + 24);

      const int krow = jloc + l31;
      const unsigned rsw = (unsigned)((l31 & 7) << 4);
      const char* kbase = (const char*)&Ks[cur][0] + krow * 128;
      bf16x8 kf0 = *(const bf16x8*)(kbase + ((0  + hi * 16) ^ rsw));
      bf16x8 kf1 = *(const bf16x8*)(kbase + ((32 + hi * 16) ^ rsw));
      bf16x8 kf2 = *(const bf16x8*)(kbase + ((64 + hi * 16) ^ rsw));
      bf16x8 kf3 = *(const bf16x8*)(kbase + ((96 + hi * 16) ^ rsw));

      __builtin_amdgcn_s_setprio(1);
      f32x16 z = {};
      f32x16 s = mfma32(kf0, qf[0], z);
      s = mfma32(kf1, qf[1], s);
      s = mfma32(kf2, qf[2], s);
      s = mfma32(kf3, qf[3], s);
      __builtin_amdgcn_s_setprio(0);

      const char* vb0 = (const char*)&Vs[cur][0] + l31 * 128;
      const char* vb1 = vb0 + 32 * 128;
      const unsigned vc0 = (unsigned)((jloc * 2 + hi * 16) ^ rsw);
      const unsigned vc1 = (unsigned)((jloc * 2 + 32 + hi * 16) ^ rsw);
      bf16x8 vf00 = *(const bf16x8*)(vb0 + vc0);
      bf16x8 vf01 = *(const bf16x8*)(vb0 + vc1);
      bf16x8 vf10 = *(const bf16x8*)(vb1 + vc0);
      bf16x8 vf11 = *(const bf16x8*)(vb1 + vc1);

      // pv = s * sc + mb  (single v_fma per element; -1e30 absorbs the product)
      float pv[16];
      #pragma unroll
      for (int e = 0; e < 4; e++) {
        pv[e]      = fmaf(s[e],      sc, mb0[e]);
        pv[4 + e]  = fmaf(s[4 + e],  sc, mb1[e]);
        pv[8 + e]  = fmaf(s[8 + e],  sc, mb2[e]);
        pv[12 + e] = fmaf(s[12 + e], sc, mb3[e]);
      }

      float t0 = fmaxf(fmaxf(pv[0],  pv[1]),  pv[2]);
      float t1 = fmaxf(fmaxf(pv[3],  pv[4]),  pv[5]);
      float t2 = fmaxf(fmaxf(pv[6],  pv[7]),  pv[8]);
      float t3 = fmaxf(fmaxf(pv[9],  pv[10]), pv[11]);
      float t4 = fmaxf(fmaxf(pv[12], pv[13]), pv[14]);
      float pm = fmaxf(fmaxf(fmaxf(t0, t1), t2), fmaxf(fmaxf(t3, t4), pv[15]));
      pm = fmaxf(pm, __shfl_xor(pm, 32));

      if (!__all(pm <= m + 8.f)) {
        float mn = fmaxf(m, pm);
        float al = exp2f(m - mn);
        lsum *= al;
        #pragma unroll
        for (int r = 0; r < 16; r++) { o0[r] *= al; o1[r] *= al; }
        m = mn;
      }

      #pragma unroll
      for (int r = 0; r < 16; r++) pv[r] = exp2f(pv[r] - m);
      float a0 = (pv[0] + pv[1]) + (pv[2] + pv[3]);
      float a1 = (pv[4] + pv[5]) + (pv[6] + pv[7]);
      float a2 = (pv[8] + pv[9]) + (pv[10] + pv[11]);
      float a3 = (pv[12] + pv[13]) + (pv[14] + pv[15]);
      float rs = (a0 + a1) + (a2 + a3);
      rs += __shfl_xor(rs, 32);
      lsum += rs;

      unsigned pk01 = cvtpk(pv[0],  pv[1]),  pk23 = cvtpk(pv[2],  pv[3]);
      unsigned pk45 = cvtpk(pv[4],  pv[5]),  pk67 = cvtpk(pv[6],  pv[7]);
      unsigned pk89 = cvtpk(pv[8],  pv[9]),  pkAB = cvtpk(pv[10], pv[11]);
      unsigned pkCD = cvtpk(pv[12], pv[13]), pkEF = cvtpk(pv[14], pv[15]);
      plswap(pk01, pk45);
      plswap(pk23, pk67);
      plswap(pk89, pkCD);
      plswap(pkAB, pkEF);
      union { unsigned u[4]; bf16x8 v; } pf0, pf1;
      pf0.u[0] = pk01; pf0.u[1] = pk23; pf0.u[2] = pk45; pf0.u[3] = pk67;
      pf1.u[0] = pk89; pf1.u[1] = pkAB; pf1.u[2] = pkCD; pf1.u[3] = pkEF;

      __builtin_amdgcn_s_setprio(1);
      o0 = mfma32(vf00, pf0.v, o0);
      o0 = mfma32(vf01, pf1.v, o0);
      o1 = mfma32(vf10, pf0.v, o1);
      o1 = mfma32(vf11, pf1.v, o1);
      __builtin_amdgcn_s_setprio(0);
    }
    __syncthreads();
  }

  float inv = lsum > 0.f ? 1.0f / lsum : 0.f;
  const int q = q0 + l31;
  ushort* op = Opart + (size_t)sp * 4194304 + ((size_t)(bh * 2048 + q)) * 64;
  #pragma unroll
  for (int grp = 0; grp < 4; grp++) {
    int d0 = grp * 8 + 4 * hi;
    uint32x2 w0, w1;
    w0[0] = cvtpk(o0[4 * grp] * inv, o0[4 * grp + 1] * inv);
    w0[1] = cvtpk(o0[4 * grp + 2] * inv, o0[4 * grp + 3] * inv);
    w1[0] = cvtpk(o1[4 * grp] * inv, o1[4 * grp + 1] * inv);
    w1[1] = cvtpk(o1[4 * grp + 2] * inv, o1[4 * grp + 3] * inv);
    *(uint32x2*)(op + d0)      = w0;
    *(uint32x2*)(op + 32 + d0) = w1;
  }
  if (hi == 0) {
    float2 v; v.x = m; v.y = lsum;
    Ml[sp * 65536 + bh * 2048 + q] = v;
  }
}

// Combine 4 split partials: AO[b,q,h*64+d] = sum_s w_s * Opart_s[bh,q,d]
__global__ __launch_bounds__(256)
void reduce_k(const ushort* __restrict__ Opart, const float2* __restrict__ Ml,
              ushort* __restrict__ AO)
{
  const int idx = blockIdx.x * 256 + threadIdx.x;   // 524288 total
  const int d8 = idx & 7, q = (idx >> 3) & 2047, bh = idx >> 14;
  const int b = bh >> 3, h = bh & 7;

  float2 ml[4];
  float M = -1e30f;
  #pragma unroll
  for (int s = 0; s < 4; s++) {
    ml[s] = Ml[s * 65536 + bh * 2048 + q];
    M = fmaxf(M, ml[s].x);
  }
  float wgt[4], L = 0.f;
  #pragma unroll
  for (int s = 0; s < 4; s++) {
    wgt[s] = ml[s].y * exp2f(ml[s].x - M);
    L += wgt[s];
  }
  float invL = 1.f / L;

  float acc[8] = {0.f,0.f,0.f,0.f,0.f,0.f,0.f,0.f};
  #pragma unroll
  for (int s = 0; s < 4; s++) {
    bf16x8 v = *(const bf16x8*)(Opart + (size_t)s * 4194304 +
                                ((size_t)(bh * 2048 + q)) * 64 + d8 * 8);
    float ws = wgt[s] * invL;
    #pragma unroll
    for (int e = 0; e < 8; e++) acc[e] += ws * bf2f(v[e]);
  }

  union { unsigned u[4]; int32x4 v; } pk;
  pk.u[0] = cvtpk(acc[0], acc[1]);
  pk.u[1] = cvtpk(acc[2], acc[3]);
  pk.u[2] = cvtpk(acc[4], acc[5]);
  pk.u[3] = cvtpk(acc[6], acc[7]);
  *(int32x4*)(AO + ((size_t)(b * 2048 + q)) * 512 + h * 64 + d8 * 8) = pk.v;
}

extern "C" void kernel_launch(void* const* d_in, const int* in_sizes, int n_in,
                              void* d_out, int out_size, void* d_ws, size_t ws_size,
                              hipStream_t stream)
{
  const float* x   = (const float*)d_in[0];
  const float* ctx = (const float*)d_in[1];
  const int*   mk  = (const int*)d_in[2];
  const float* Wq  = (const float*)d_in[3];
  const float* Wk  = (const float*)d_in[4];
  const float* Wv  = (const float*)d_in[5];
  const float* Wo  = (const float*)d_in[6];
  const float* bo  = (const float*)d_in[7];
  float* out = (float*)d_out;

  // Workspace plan (~59 MB; ws >= 66 MB proven in earlier rounds):
  //  [0,8M):   Qb  -- later aliased as AO (reduce_k output)
  //  [8M,16M): Kb
  //  [16M,24M):VT
  //  [24M,25M):WoT [1024][512] bf16
  //  [25M,25M+32K): mb  float[4][2048]
  //  then R2 time-shared:
  //     prepass view: xb 16M | cb 12M | WqT 1M | WkT .75M | WvT .75M
  //     attn view:    Opart 32M | Ml 2M
  ushort* Qb  = (ushort*)d_ws;
  ushort* Kb  = Qb + 4194304;
  ushort* VT  = Kb + 4194304;
  ushort* WoT = VT + 4194304;
  float*  mb  = (float*)(WoT + 524288);
  ushort* R2  = WoT + 524288 + 16384;     // after mb (8192 floats)
  ushort* xb  = R2;
  ushort* cb  = xb + 8388608;
  ushort* WqT = cb + 6291456;
  ushort* WkT = WqT + 524288;
  ushort* WvT = WkT + 393216;
  ushort* Opart = R2;
  float2* Ml    = (float2*)(R2 + 16777216);
  ushort* AO    = Qb;

  cvt_k<<<2048, 256, 0, stream>>>(x, ctx, xb, cb, mk, mb);
  wtcvt_k<<<448, 256, 0, stream>>>(Wq, Wk, Wv, Wo, WqT, WkT, WvT, WoT);
  mm_k<0><<<768, 256, 0, stream>>>(xb, cb, WqT, WkT, WvT, Qb, Kb, VT,
                                   nullptr, nullptr, nullptr, nullptr);
  attn_k<<<dim3(32, 8, 4), 512, 0, stream>>>(Qb, Kb, VT, mb, Opart, Ml);
  reduce_k<<<2048, 256, 0, stream>>>(Opart, Ml, AO);
  mm_k<1><<<512, 256, 0, stream>>>(nullptr, nullptr, nullptr, nullptr, nullptr,
                                   nullptr, nullptr, nullptr, AO, WoT, out, bo);
}